// Round 1
// baseline (5863.285 us; speedup 1.0000x reference)
//
#include <hip/hip_runtime.h>
#include <hip/hip_bf16.h>
#include <math.h>

#define NN 100000
#define NE 1280000
#define NG 256
#define HID 128
#define EMB 64
#define BN_EPS 1e-5f

// ---------------------------------------------------------------- utilities
__global__ void detect_i64_kernel(const void* __restrict__ ei, int* __restrict__ flag) {
    if (threadIdx.x == 0 && blockIdx.x == 0) {
        // If data is int32 pairs, reading as u64 gives lo + hi*2^32 with hi ~U[0,100000) -> almost surely >= 2^32.
        // If data is genuine int64 indices (< 100000), every value < 2^32.
        const unsigned long long* p = (const unsigned long long*)ei;
        int is64 = 1;
        #pragma unroll
        for (int i = 0; i < 16; ++i)
            if (p[i] >= (1ull << 32)) is64 = 0;
        *flag = is64;
    }
}

__device__ __forceinline__ int load_idx(const void* p, int i, bool is64) {
    return is64 ? (int)((const long long*)p)[i] : ((const int*)p)[i];
}

// ---------------------------------------------------------------- edge scatter: out[dst] += x[src]
template<int F>
__global__ __launch_bounds__(256) void scatter_kernel(const float* __restrict__ x,
                                                      const void* __restrict__ ei,
                                                      float* out,
                                                      const int* __restrict__ flag) {
    const bool is64 = (*flag != 0);
    const int lane = threadIdx.x & 63;
    int wv = (blockIdx.x * blockDim.x + threadIdx.x) >> 6;
    const int nw = (gridDim.x * blockDim.x) >> 6;
    for (int e = wv; e < NE; e += nw) {
        const int s = load_idx(ei, e, is64);
        const int d = load_idx(ei, NE + e, is64);
        if (F == 64) {
            const float v = x[s * 64 + lane];
            unsafeAtomicAdd(&out[d * 64 + lane], v);
        } else {
            const float2 v = *(const float2*)&x[s * 128 + lane * 2];
            unsafeAtomicAdd(&out[d * 128 + lane * 2 + 0], v.x);
            unsafeAtomicAdd(&out[d * 128 + lane * 2 + 1], v.y);
        }
    }
}

// ---------------------------------------------------------------- C = (X + S) @ W + bias   (NN x FIN) @ (FIN x 128)
// NOTE: S may alias C (layers 2/3). Each block reads only its own 64 rows of S, and all
// reads complete (LDS-staged, barriered) before the epilogue stores to the same rows.
template<int FIN>
__global__ __launch_bounds__(256) void gemm_kernel(const float* __restrict__ X,
                                                   const float* S,
                                                   const float* __restrict__ W,
                                                   const float* __restrict__ bias,
                                                   float* C) {
    __shared__ float xs[64][33];   // +1 pad: row stride 33 breaks bank aliasing
    __shared__ float ws[32][128];
    const int t = threadIdx.x;
    const int r0 = blockIdx.x * 64;
    const int ry = t >> 4, cx = t & 15, c0 = cx * 8;

    float acc[4][8];
    #pragma unroll
    for (int i = 0; i < 4; ++i)
        #pragma unroll
        for (int j = 0; j < 8; ++j) acc[i][j] = 0.f;

    for (int k0 = 0; k0 < FIN; k0 += 32) {
        {   // stage X+S tile (64 x 32)
            const int rr0 = t >> 3, kg = (t & 7) * 4;
            #pragma unroll
            for (int it = 0; it < 2; ++it) {
                const int rr = rr0 + it * 32;
                const int r = r0 + rr;
                float4 v = make_float4(0.f, 0.f, 0.f, 0.f);
                if (r < NN) {
                    const float4 a = *(const float4*)&X[r * FIN + k0 + kg];
                    const float4 b = *(const float4*)&S[r * FIN + k0 + kg];
                    v.x = a.x + b.x; v.y = a.y + b.y; v.z = a.z + b.z; v.w = a.w + b.w;
                }
                xs[rr][kg + 0] = v.x; xs[rr][kg + 1] = v.y;
                xs[rr][kg + 2] = v.z; xs[rr][kg + 3] = v.w;
            }
            // stage W tile (32 x 128)
            const int kk0 = t >> 5, cg = (t & 31) * 4;
            #pragma unroll
            for (int it = 0; it < 4; ++it) {
                const int kk = kk0 + it * 8;
                *(float4*)&ws[kk][cg] = *(const float4*)&W[(k0 + kk) * HID + cg];
            }
        }
        __syncthreads();
        #pragma unroll
        for (int k = 0; k < 32; ++k) {
            float xv[4], wv[8];
            #pragma unroll
            for (int i = 0; i < 4; ++i) xv[i] = xs[ry * 4 + i][k];
            *(float4*)&wv[0] = *(const float4*)&ws[k][c0];
            *(float4*)&wv[4] = *(const float4*)&ws[k][c0 + 4];
            #pragma unroll
            for (int i = 0; i < 4; ++i)
                #pragma unroll
                for (int j = 0; j < 8; ++j) acc[i][j] = fmaf(xv[i], wv[j], acc[i][j]);
        }
        __syncthreads();
    }
    float bv[8];
    *(float4*)&bv[0] = *(const float4*)&bias[c0];
    *(float4*)&bv[4] = *(const float4*)&bias[c0 + 4];
    #pragma unroll
    for (int i = 0; i < 4; ++i) {
        const int r = r0 + ry * 4 + i;
        if (r < NN) {
            float4 o0 = make_float4(acc[i][0] + bv[0], acc[i][1] + bv[1],
                                    acc[i][2] + bv[2], acc[i][3] + bv[3]);
            float4 o1 = make_float4(acc[i][4] + bv[4], acc[i][5] + bv[5],
                                    acc[i][6] + bv[6], acc[i][7] + bv[7]);
            *(float4*)&C[r * HID + c0 + 0] = o0;
            *(float4*)&C[r * HID + c0 + 4] = o1;
        }
    }
}

// ---------------------------------------------------------------- BN column stats (sum, sumsq)
__global__ __launch_bounds__(256) void bn_stats(const float* __restrict__ C, float* stats) {
    const int t = threadIdx.x;
    const int c = t & 127, half = t >> 7;
    const int rbeg = blockIdx.x * 256;
    const int rend = min(rbeg + 256, NN);
    float s = 0.f, sq = 0.f;
    for (int r = rbeg + half; r < rend; r += 2) {
        const float v = C[r * HID + c];
        s += v; sq = fmaf(v, v, sq);
    }
    __shared__ float red[512];
    red[t] = s; red[t + 256] = sq;
    __syncthreads();
    if (t < 128) {
        unsafeAtomicAdd(&stats[c],       red[t] + red[t + 128]);
        unsafeAtomicAdd(&stats[128 + c], red[t + 256] + red[t + 384]);
    }
}

__global__ void bn_prep(const float* __restrict__ stats, const float* __restrict__ gamma,
                        const float* __restrict__ beta, float* __restrict__ coef) {
    const int c = threadIdx.x;  // 128
    const float inv_n = 1.f / (float)NN;
    const float mu = stats[c] * inv_n;
    const float var = stats[128 + c] * inv_n - mu * mu;
    const float a = gamma[c] * rsqrtf(var + BN_EPS);
    coef[c] = a;
    coef[128 + c] = fmaf(-mu, a, beta[c]);
}

__global__ __launch_bounds__(256) void bn_apply_relu(const float* __restrict__ C,
                                                     const float* __restrict__ coef,
                                                     float* __restrict__ out) {
    __shared__ float ca[128], cb[128];
    if (threadIdx.x < 128) {
        ca[threadIdx.x] = coef[threadIdx.x];
        cb[threadIdx.x] = coef[128 + threadIdx.x];
    }
    __syncthreads();
    const int total = NN * HID / 4;
    for (int i = blockIdx.x * blockDim.x + threadIdx.x; i < total; i += gridDim.x * blockDim.x) {
        float4 v = ((const float4*)C)[i];
        const int c0 = (i & 31) * 4;
        v.x = fmaxf(fmaf(v.x, ca[c0 + 0], cb[c0 + 0]), 0.f);
        v.y = fmaxf(fmaf(v.y, ca[c0 + 1], cb[c0 + 1]), 0.f);
        v.z = fmaxf(fmaf(v.z, ca[c0 + 2], cb[c0 + 2]), 0.f);
        v.w = fmaxf(fmaf(v.w, ca[c0 + 3], cb[c0 + 3]), 0.f);
        ((float4*)out)[i] = v;
    }
}

// ---------------------------------------------------------------- global mean pool (batch is sorted -> run compression)
__global__ __launch_bounds__(128) void pool_kernel(const float* __restrict__ x,
                                                   const void* __restrict__ batch,
                                                   float* pooled, float* cnt,
                                                   const int* __restrict__ flag) {
    const bool is64 = (*flag != 0);
    const int c = threadIdx.x;  // 128
    const int rbeg = blockIdx.x * 512;
    if (rbeg >= NN) return;
    const int rend = min(rbeg + 512, NN);
    int gprev = load_idx(batch, rbeg, is64);
    float acc = 0.f; int run = 0;
    for (int r = rbeg; r < rend; ++r) {
        const int g = load_idx(batch, r, is64);
        if (g != gprev) {
            unsafeAtomicAdd(&pooled[gprev * HID + c], acc);
            if (c == 0) unsafeAtomicAdd(&cnt[gprev], (float)run);
            acc = 0.f; run = 0; gprev = g;
        }
        acc += x[r * HID + c];
        ++run;
    }
    unsafeAtomicAdd(&pooled[gprev * HID + c], acc);
    if (c == 0) unsafeAtomicAdd(&cnt[gprev], (float)run);
}

__global__ __launch_bounds__(64) void pool_proj(const float* __restrict__ pooled,
                                                const float* __restrict__ cnt,
                                                const float* __restrict__ Wf,
                                                const float* __restrict__ bf,
                                                float* __restrict__ v) {
    const int g = blockIdx.x, c = threadIdx.x;  // 64
    const float inv = 1.f / fmaxf(cnt[g], 1.f);
    float acc = 0.f;
    for (int k = 0; k < HID; ++k) acc = fmaf(pooled[g * HID + k], Wf[k * EMB + c], acc);
    v[g * EMB + c] = fmaf(acc, inv, bf[c]);
}

// ---------------------------------------------------------------- classifier head
__global__ __launch_bounds__(256) void classifier(const float* __restrict__ v1,
                                                  const float* __restrict__ v2,
                                                  const float* __restrict__ Wc1,
                                                  const float* __restrict__ bc1,
                                                  const float* __restrict__ Wc2,
                                                  const float* __restrict__ bc2,
                                                  float* __restrict__ out) {
    const int g = threadIdx.x;
    if (g >= NG) return;
    float d[EMB];
    #pragma unroll
    for (int c = 0; c < EMB; ++c) d[c] = fabsf(v1[g * EMB + c] - v2[g * EMB + c]);
    float o = bc2[0];
    for (int j = 0; j < 32; ++j) {
        float h = bc1[j];
        #pragma unroll
        for (int c = 0; c < EMB; ++c) h = fmaf(d[c], Wc1[c * 32 + j], h);
        h = fmaxf(h, 0.f);
        o = fmaf(h, Wc2[j], o);
    }
    out[g] = 1.f / (1.f + expf(-o));
}

// ---------------------------------------------------------------- launch
extern "C" void kernel_launch(void* const* d_in, const int* in_sizes, int n_in,
                              void* d_out, int out_size, void* d_ws, size_t ws_size,
                              hipStream_t stream) {
    const float* x1 = (const float*)d_in[0];
    const float* x2 = (const float*)d_in[1];
    const void* ei1 = d_in[2];
    const void* ei2 = d_in[3];
    const void* bt1 = d_in[4];
    const void* bt2 = d_in[5];
    const float* W[3]  = {(const float*)d_in[6],  (const float*)d_in[10], (const float*)d_in[14]};
    const float* bb[3] = {(const float*)d_in[7],  (const float*)d_in[11], (const float*)d_in[15]};
    const float* gg[3] = {(const float*)d_in[8],  (const float*)d_in[12], (const float*)d_in[16]};
    const float* be[3] = {(const float*)d_in[9],  (const float*)d_in[13], (const float*)d_in[17]};
    const float* Wf  = (const float*)d_in[18];
    const float* bfv = (const float*)d_in[19];
    const float* Wc1 = (const float*)d_in[20];
    const float* bc1 = (const float*)d_in[21];
    const float* Wc2 = (const float*)d_in[22];
    const float* bc2 = (const float*)d_in[23];

    float* A  = (float*)d_ws;                 // N x 128 activations
    float* B  = A + (size_t)NN * HID;         // N x 128 scatter accumulator / GEMM out
    float* SM = B + (size_t)NN * HID;         // small region
    int*   flag   = (int*)SM;                 // [16]
    float* stats  = SM + 16;                  // 6 passes x 512 (sum,sumsq,coefA,coefB)
    float* pooled = stats + 6 * 512;          // 2 x G x 128
    float* cnt    = pooled + 2 * NG * HID;    // 2 x G
    float* vv     = cnt + 2 * NG;             // 2 x G x 64

    hipMemsetAsync(SM, 0, (size_t)(16 + 6 * 512 + 2 * NG * HID + 2 * NG) * sizeof(float), stream);
    detect_i64_kernel<<<1, 64, 0, stream>>>(ei1, flag);

    for (int side = 0; side < 2; ++side) {
        const float* x0 = side ? x2 : x1;
        const void* ei  = side ? ei2 : ei1;
        const void* bt  = side ? bt2 : bt1;
        float* ppool = pooled + side * NG * HID;
        float* pcnt  = cnt + side * NG;
        float* pv    = vv + side * NG * EMB;

        // ---- layer 1 (FIN=64): scatter->B, C=A, BN in-place on A
        hipMemsetAsync(B, 0, (size_t)NN * 64 * sizeof(float), stream);
        scatter_kernel<64><<<4096, 256, 0, stream>>>(x0, ei, B, flag);
        gemm_kernel<64><<<(NN + 63) / 64, 256, 0, stream>>>(x0, B, W[0], bb[0], A);
        {
            float* st = stats + (side * 3 + 0) * 512;
            bn_stats<<<(NN + 255) / 256, 256, 0, stream>>>(A, st);
            bn_prep<<<1, 128, 0, stream>>>(st, gg[0], be[0], st + 256);
            bn_apply_relu<<<2048, 256, 0, stream>>>(A, st + 256, A);
        }
        // ---- layers 2,3 (FIN=128): scatter->B, C=B (aliased), BN reads B writes A
        for (int l = 1; l < 3; ++l) {
            hipMemsetAsync(B, 0, (size_t)NN * HID * sizeof(float), stream);
            scatter_kernel<128><<<4096, 256, 0, stream>>>(A, ei, B, flag);
            gemm_kernel<128><<<(NN + 63) / 64, 256, 0, stream>>>(A, B, W[l], bb[l], B);
            float* st = stats + (side * 3 + l) * 512;
            bn_stats<<<(NN + 255) / 256, 256, 0, stream>>>(B, st);
            bn_prep<<<1, 128, 0, stream>>>(st, gg[l], be[l], st + 256);
            bn_apply_relu<<<2048, 256, 0, stream>>>(B, st + 256, A);
        }
        pool_kernel<<<(NN + 511) / 512, 128, 0, stream>>>(A, bt, ppool, pcnt, flag);
        pool_proj<<<NG, 64, 0, stream>>>(ppool, pcnt, Wf, bfv, pv);
    }
    classifier<<<1, 256, 0, stream>>>(vv, vv + NG * EMB, Wc1, bc1, Wc2, bc2, (float*)d_out);
}

// Round 2
// 2419.975 us; speedup vs baseline: 2.4229x; 2.4229x over previous
//
#include <hip/hip_runtime.h>
#include <hip/hip_bf16.h>
#include <math.h>

#define NN 100000
#define NE 1280000
#define NG 256
#define HID 128
#define EMB 64
#define BN_EPS 1e-5f

// ---------------------------------------------------------------- utilities
__global__ void detect_i64_kernel(const void* __restrict__ ei, int* __restrict__ flag) {
    if (threadIdx.x == 0 && blockIdx.x == 0) {
        // int32 pairs read as u64 -> hi word ~U[0,100000) -> almost surely >= 2^32 somewhere.
        const unsigned long long* p = (const unsigned long long*)ei;
        int is64 = 1;
        #pragma unroll
        for (int i = 0; i < 16; ++i)
            if (p[i] >= (1ull << 32)) is64 = 0;
        *flag = is64;
    }
}

__device__ __forceinline__ int load_idx(const void* p, int i, bool is64) {
    return is64 ? (int)((const long long*)p)[i] : ((const int*)p)[i];
}

// ---------------------------------------------------------------- CSR build (dst-sorted)
__global__ __launch_bounds__(256) void csr_hist(const void* __restrict__ ei,
                                                int* __restrict__ deg,
                                                const int* __restrict__ flag) {
    const bool is64 = (*flag != 0);
    const int i = blockIdx.x * blockDim.x + threadIdx.x;
    if (i < NE) atomicAdd(&deg[load_idx(ei, NE + i, is64)], 1);
}

__global__ __launch_bounds__(1024) void csr_scan(const int* __restrict__ deg,
                                                 int* __restrict__ rowptr,
                                                 int* __restrict__ cursor) {
    __shared__ int sums[1024];
    const int t = threadIdx.x;
    const int per = (NN + 1023) / 1024;  // 98
    const int beg = t * per, end = min(beg + per, NN);
    int s = 0;
    for (int i = beg; i < end; ++i) s += deg[i];
    sums[t] = s;
    __syncthreads();
    for (int off = 1; off < 1024; off <<= 1) {   // Hillis-Steele inclusive scan
        int v = (t >= off) ? sums[t - off] : 0;
        __syncthreads();
        sums[t] += v;
        __syncthreads();
    }
    int run = (t == 0) ? 0 : sums[t - 1];
    for (int i = beg; i < end; ++i) {
        const int dv = deg[i];
        rowptr[i] = run;
        cursor[i] = run;
        run += dv;
    }
    if (t == 1023) rowptr[NN] = sums[1023];
}

__global__ __launch_bounds__(256) void csr_fill(const void* __restrict__ ei,
                                                int* __restrict__ cursor,
                                                int* __restrict__ col,
                                                const int* __restrict__ flag) {
    const bool is64 = (*flag != 0);
    const int i = blockIdx.x * blockDim.x + threadIdx.x;
    if (i < NE) {
        const int d = load_idx(ei, NE + i, is64);
        const int pos = atomicAdd(&cursor[d], 1);
        col[pos] = load_idx(ei, i, is64);
    }
}

// ---------------------------------------------------------------- gather aggregation: out[d] = x[d] + sum_{j->d} x[j]
// one wave per node; lanes hold columns; reads are contiguous 256/512B rows (L3-resident x)
template<int F>
__global__ __launch_bounds__(256) void gather_kernel(const float* __restrict__ x,
                                                     const int* __restrict__ rowptr,
                                                     const int* __restrict__ col,
                                                     float* __restrict__ out) {
    const int node = (blockIdx.x * blockDim.x + threadIdx.x) >> 6;
    const int lane = threadIdx.x & 63;
    if (node >= NN) return;
    const int beg = rowptr[node], end = rowptr[node + 1];
    if (F == 64) {
        float acc = x[node * 64 + lane];
        int e = beg;
        for (; e + 1 < end; e += 2) {
            const int s0 = col[e], s1 = col[e + 1];
            const float v0 = x[s0 * 64 + lane];
            const float v1 = x[s1 * 64 + lane];
            acc += v0 + v1;
        }
        if (e < end) acc += x[col[e] * 64 + lane];
        out[node * 64 + lane] = acc;
    } else {
        float2 acc = *(const float2*)&x[node * 128 + lane * 2];
        int e = beg;
        for (; e + 1 < end; e += 2) {
            const int s0 = col[e], s1 = col[e + 1];
            const float2 v0 = *(const float2*)&x[s0 * 128 + lane * 2];
            const float2 v1 = *(const float2*)&x[s1 * 128 + lane * 2];
            acc.x += v0.x + v1.x;
            acc.y += v0.y + v1.y;
        }
        if (e < end) {
            const float2 v = *(const float2*)&x[col[e] * 128 + lane * 2];
            acc.x += v.x; acc.y += v.y;
        }
        *(float2*)&out[node * 128 + lane * 2] = acc;
    }
}

// ---------------------------------------------------------------- C = M @ W + bias   (NN x FIN) @ (FIN x 128)
// NOTE: M may alias C (layers 2/3). Each block reads only its own 64 rows of M and all
// reads complete (LDS-staged, barriered) before the epilogue stores to the same rows.
template<int FIN>
__global__ __launch_bounds__(256) void gemm_kernel(const float* M,
                                                   const float* __restrict__ W,
                                                   const float* __restrict__ bias,
                                                   float* C) {
    __shared__ float xs[64][33];   // +1 pad breaks bank aliasing
    __shared__ float ws[32][128];
    const int t = threadIdx.x;
    const int r0 = blockIdx.x * 64;
    const int ry = t >> 4, cx = t & 15, c0 = cx * 8;

    float acc[4][8];
    #pragma unroll
    for (int i = 0; i < 4; ++i)
        #pragma unroll
        for (int j = 0; j < 8; ++j) acc[i][j] = 0.f;

    for (int k0 = 0; k0 < FIN; k0 += 32) {
        {   // stage M tile (64 x 32)
            const int rr0 = t >> 3, kg = (t & 7) * 4;
            #pragma unroll
            for (int it = 0; it < 2; ++it) {
                const int rr = rr0 + it * 32;
                const int r = r0 + rr;
                float4 v = make_float4(0.f, 0.f, 0.f, 0.f);
                if (r < NN) v = *(const float4*)&M[r * FIN + k0 + kg];
                xs[rr][kg + 0] = v.x; xs[rr][kg + 1] = v.y;
                xs[rr][kg + 2] = v.z; xs[rr][kg + 3] = v.w;
            }
            // stage W tile (32 x 128)
            const int kk0 = t >> 5, cg = (t & 31) * 4;
            #pragma unroll
            for (int it = 0; it < 4; ++it) {
                const int kk = kk0 + it * 8;
                *(float4*)&ws[kk][cg] = *(const float4*)&W[(k0 + kk) * HID + cg];
            }
        }
        __syncthreads();
        #pragma unroll
        for (int k = 0; k < 32; ++k) {
            float xv[4], wv[8];
            #pragma unroll
            for (int i = 0; i < 4; ++i) xv[i] = xs[ry * 4 + i][k];
            *(float4*)&wv[0] = *(const float4*)&ws[k][c0];
            *(float4*)&wv[4] = *(const float4*)&ws[k][c0 + 4];
            #pragma unroll
            for (int i = 0; i < 4; ++i)
                #pragma unroll
                for (int j = 0; j < 8; ++j) acc[i][j] = fmaf(xv[i], wv[j], acc[i][j]);
        }
        __syncthreads();
    }
    float bv[8];
    *(float4*)&bv[0] = *(const float4*)&bias[c0];
    *(float4*)&bv[4] = *(const float4*)&bias[c0 + 4];
    #pragma unroll
    for (int i = 0; i < 4; ++i) {
        const int r = r0 + ry * 4 + i;
        if (r < NN) {
            float4 o0 = make_float4(acc[i][0] + bv[0], acc[i][1] + bv[1],
                                    acc[i][2] + bv[2], acc[i][3] + bv[3]);
            float4 o1 = make_float4(acc[i][4] + bv[4], acc[i][5] + bv[5],
                                    acc[i][6] + bv[6], acc[i][7] + bv[7]);
            *(float4*)&C[r * HID + c0 + 0] = o0;
            *(float4*)&C[r * HID + c0 + 4] = o1;
        }
    }
}

// ---------------------------------------------------------------- BN column stats (sum, sumsq)
__global__ __launch_bounds__(256) void bn_stats(const float* __restrict__ C, float* stats) {
    const int t = threadIdx.x;
    const int c = t & 127, half = t >> 7;
    const int rbeg = blockIdx.x * 256;
    const int rend = min(rbeg + 256, NN);
    float s = 0.f, sq = 0.f;
    for (int r = rbeg + half; r < rend; r += 2) {
        const float v = C[r * HID + c];
        s += v; sq = fmaf(v, v, sq);
    }
    __shared__ float red[512];
    red[t] = s; red[t + 256] = sq;
    __syncthreads();
    if (t < 128) {
        unsafeAtomicAdd(&stats[c],       red[t] + red[t + 128]);
        unsafeAtomicAdd(&stats[128 + c], red[t + 256] + red[t + 384]);
    }
}

__global__ void bn_prep(const float* __restrict__ stats, const float* __restrict__ gamma,
                        const float* __restrict__ beta, float* __restrict__ coef) {
    const int c = threadIdx.x;  // 128
    const float inv_n = 1.f / (float)NN;
    const float mu = stats[c] * inv_n;
    const float var = stats[128 + c] * inv_n - mu * mu;
    const float a = gamma[c] * rsqrtf(var + BN_EPS);
    coef[c] = a;
    coef[128 + c] = fmaf(-mu, a, beta[c]);
}

__global__ __launch_bounds__(256) void bn_apply_relu(const float* __restrict__ C,
                                                     const float* __restrict__ coef,
                                                     float* __restrict__ out) {
    __shared__ float ca[128], cb[128];
    if (threadIdx.x < 128) {
        ca[threadIdx.x] = coef[threadIdx.x];
        cb[threadIdx.x] = coef[128 + threadIdx.x];
    }
    __syncthreads();
    const int total = NN * HID / 4;
    for (int i = blockIdx.x * blockDim.x + threadIdx.x; i < total; i += gridDim.x * blockDim.x) {
        float4 v = ((const float4*)C)[i];
        const int c0 = (i & 31) * 4;
        v.x = fmaxf(fmaf(v.x, ca[c0 + 0], cb[c0 + 0]), 0.f);
        v.y = fmaxf(fmaf(v.y, ca[c0 + 1], cb[c0 + 1]), 0.f);
        v.z = fmaxf(fmaf(v.z, ca[c0 + 2], cb[c0 + 2]), 0.f);
        v.w = fmaxf(fmaf(v.w, ca[c0 + 3], cb[c0 + 3]), 0.f);
        ((float4*)out)[i] = v;
    }
}

// ---------------------------------------------------------------- global mean pool (batch sorted -> run compression)
__global__ __launch_bounds__(128) void pool_kernel(const float* __restrict__ x,
                                                   const void* __restrict__ batch,
                                                   float* pooled, float* cnt,
                                                   const int* __restrict__ flag) {
    const bool is64 = (*flag != 0);
    const int c = threadIdx.x;  // 128
    const int rbeg = blockIdx.x * 512;
    if (rbeg >= NN) return;
    const int rend = min(rbeg + 512, NN);
    int gprev = load_idx(batch, rbeg, is64);
    float acc = 0.f; int run = 0;
    for (int r = rbeg; r < rend; ++r) {
        const int g = load_idx(batch, r, is64);
        if (g != gprev) {
            unsafeAtomicAdd(&pooled[gprev * HID + c], acc);
            if (c == 0) unsafeAtomicAdd(&cnt[gprev], (float)run);
            acc = 0.f; run = 0; gprev = g;
        }
        acc += x[r * HID + c];
        ++run;
    }
    unsafeAtomicAdd(&pooled[gprev * HID + c], acc);
    if (c == 0) unsafeAtomicAdd(&cnt[gprev], (float)run);
}

__global__ __launch_bounds__(64) void pool_proj(const float* __restrict__ pooled,
                                                const float* __restrict__ cnt,
                                                const float* __restrict__ Wf,
                                                const float* __restrict__ bf,
                                                float* __restrict__ v) {
    const int g = blockIdx.x, c = threadIdx.x;  // 64
    const float inv = 1.f / fmaxf(cnt[g], 1.f);
    float acc = 0.f;
    for (int k = 0; k < HID; ++k) acc = fmaf(pooled[g * HID + k], Wf[k * EMB + c], acc);
    v[g * EMB + c] = fmaf(acc, inv, bf[c]);
}

// ---------------------------------------------------------------- classifier head
__global__ __launch_bounds__(256) void classifier(const float* __restrict__ v1,
                                                  const float* __restrict__ v2,
                                                  const float* __restrict__ Wc1,
                                                  const float* __restrict__ bc1,
                                                  const float* __restrict__ Wc2,
                                                  const float* __restrict__ bc2,
                                                  float* __restrict__ out) {
    const int g = threadIdx.x;
    if (g >= NG) return;
    float d[EMB];
    #pragma unroll
    for (int c = 0; c < EMB; ++c) d[c] = fabsf(v1[g * EMB + c] - v2[g * EMB + c]);
    float o = bc2[0];
    for (int j = 0; j < 32; ++j) {
        float h = bc1[j];
        #pragma unroll
        for (int c = 0; c < EMB; ++c) h = fmaf(d[c], Wc1[c * 32 + j], h);
        h = fmaxf(h, 0.f);
        o = fmaf(h, Wc2[j], o);
    }
    out[g] = 1.f / (1.f + expf(-o));
}

// ---------------------------------------------------------------- launch
extern "C" void kernel_launch(void* const* d_in, const int* in_sizes, int n_in,
                              void* d_out, int out_size, void* d_ws, size_t ws_size,
                              hipStream_t stream) {
    const float* x1 = (const float*)d_in[0];
    const float* x2 = (const float*)d_in[1];
    const void* ei1 = d_in[2];
    const void* ei2 = d_in[3];
    const void* bt1 = d_in[4];
    const void* bt2 = d_in[5];
    const float* W[3]  = {(const float*)d_in[6],  (const float*)d_in[10], (const float*)d_in[14]};
    const float* bb[3] = {(const float*)d_in[7],  (const float*)d_in[11], (const float*)d_in[15]};
    const float* gg[3] = {(const float*)d_in[8],  (const float*)d_in[12], (const float*)d_in[16]};
    const float* be[3] = {(const float*)d_in[9],  (const float*)d_in[13], (const float*)d_in[17]};
    const float* Wf  = (const float*)d_in[18];
    const float* bfv = (const float*)d_in[19];
    const float* Wc1 = (const float*)d_in[20];
    const float* bc1 = (const float*)d_in[21];
    const float* Wc2 = (const float*)d_in[22];
    const float* bc2 = (const float*)d_in[23];

    float* A  = (float*)d_ws;                 // N x 128 activations
    float* B  = A + (size_t)NN * HID;         // N x 128 aggregation / GEMM out
    float* SM = B + (size_t)NN * HID;         // small region
    int*   flag   = (int*)SM;                 // [16]
    float* stats  = SM + 16;                  // 6 x 512 (sum,sumsq | coefA,coefB)
    float* pooled = stats + 6 * 512;          // 2 x G x 128
    float* cnt    = pooled + 2 * NG * HID;    // 2 x G
    float* vv     = cnt + 2 * NG;             // 2 x G x 64
    // CSR region (rebuilt per side; 6.6 MB)
    int* deg    = (int*)(vv + 2 * NG * EMB);
    int* rowptr = deg + NN;
    int* cursor = rowptr + NN + 1;
    int* col    = cursor + NN;

    hipMemsetAsync(SM, 0, (size_t)(16 + 6 * 512 + 2 * NG * HID + 2 * NG) * sizeof(float), stream);
    detect_i64_kernel<<<1, 64, 0, stream>>>(ei1, flag);

    const int EB = (NE + 255) / 256;          // edge-parallel blocks
    const int GB = (NN * 64 + 255) / 256;     // wave-per-node blocks

    for (int side = 0; side < 2; ++side) {
        const float* x0 = side ? x2 : x1;
        const void* ei  = side ? ei2 : ei1;
        const void* bt  = side ? bt2 : bt1;
        float* ppool = pooled + side * NG * HID;
        float* pcnt  = cnt + side * NG;
        float* pv    = vv + side * NG * EMB;

        // ---- build dst-CSR for this side
        hipMemsetAsync(deg, 0, (size_t)NN * sizeof(int), stream);
        csr_hist<<<EB, 256, 0, stream>>>(ei, deg, flag);
        csr_scan<<<1, 1024, 0, stream>>>(deg, rowptr, cursor);
        csr_fill<<<EB, 256, 0, stream>>>(ei, cursor, col, flag);

        // ---- layer 1 (FIN=64): gather x0 -> B, gemm B -> A, BN in-place on A
        gather_kernel<64><<<GB, 256, 0, stream>>>(x0, rowptr, col, B);
        gemm_kernel<64><<<(NN + 63) / 64, 256, 0, stream>>>(B, W[0], bb[0], A);
        {
            float* st = stats + (side * 3 + 0) * 512;
            bn_stats<<<(NN + 255) / 256, 256, 0, stream>>>(A, st);
            bn_prep<<<1, 128, 0, stream>>>(st, gg[0], be[0], st + 256);
            bn_apply_relu<<<2048, 256, 0, stream>>>(A, st + 256, A);
        }
        // ---- layers 2,3 (FIN=128): gather A -> B, gemm B -> B (in-place safe), BN B -> A
        for (int l = 1; l < 3; ++l) {
            gather_kernel<128><<<GB, 256, 0, stream>>>(A, rowptr, col, B);
            gemm_kernel<128><<<(NN + 63) / 64, 256, 0, stream>>>(B, W[l], bb[l], B);
            float* st = stats + (side * 3 + l) * 512;
            bn_stats<<<(NN + 255) / 256, 256, 0, stream>>>(B, st);
            bn_prep<<<1, 128, 0, stream>>>(st, gg[l], be[l], st + 256);
            bn_apply_relu<<<2048, 256, 0, stream>>>(B, st + 256, A);
        }
        pool_kernel<<<(NN + 511) / 512, 128, 0, stream>>>(A, bt, ppool, pcnt, flag);
        pool_proj<<<NG, 64, 0, stream>>>(ppool, pcnt, Wf, bfv, pv);
    }
    classifier<<<1, 256, 0, stream>>>(vv, vv + NG * EMB, Wc1, bc1, Wc2, bc2, (float*)d_out);
}

// Round 3
// 1837.422 us; speedup vs baseline: 3.1910x; 1.3170x over previous
//
#include <hip/hip_runtime.h>
#include <hip/hip_bf16.h>
#include <math.h>

#define NN 100000
#define NE 1280000
#define NG 256
#define HID 128
#define EMB 64
#define BN_EPS 1e-5f
#define SB 1024
#define SNB ((NN + SB - 1) / SB)   // 98

// ---------------------------------------------------------------- utilities
__global__ void detect_i64_kernel(const void* __restrict__ ei, int* __restrict__ flag) {
    if (threadIdx.x == 0 && blockIdx.x == 0) {
        // int32 pairs read as u64 -> hi word ~U[0,100000) -> almost surely >= 2^32 somewhere.
        const unsigned long long* p = (const unsigned long long*)ei;
        int is64 = 1;
        #pragma unroll
        for (int i = 0; i < 16; ++i)
            if (p[i] >= (1ull << 32)) is64 = 0;
        *flag = is64;
    }
}

__device__ __forceinline__ int load_idx(const void* p, int i, bool is64) {
    return is64 ? (int)((const long long*)p)[i] : ((const int*)p)[i];
}

// ---------------------------------------------------------------- CSR build (dst-sorted)
__global__ __launch_bounds__(256) void csr_hist(const void* __restrict__ ei,
                                                int* __restrict__ deg,
                                                const int* __restrict__ flag) {
    const bool is64 = (*flag != 0);
    const int i = blockIdx.x * blockDim.x + threadIdx.x;
    if (i < NE) atomicAdd(&deg[load_idx(ei, NE + i, is64)], 1);
}

// phase A: per-block (1024 elems) totals
__global__ __launch_bounds__(256) void scan_block_sums(const int* __restrict__ deg,
                                                       int* __restrict__ bsum) {
    const int t = threadIdx.x;
    const int base = blockIdx.x * SB + t * 4;
    int s = 0;
    #pragma unroll
    for (int k = 0; k < 4; ++k) {
        const int i = base + k;
        if (i < NN) s += deg[i];
    }
    __shared__ int red[256];
    red[t] = s;
    __syncthreads();
    for (int off = 128; off > 0; off >>= 1) {
        if (t < off) red[t] += red[t + off];
        __syncthreads();
    }
    if (t == 0) bsum[blockIdx.x] = red[0];
}

// phase B: scan the 98 block totals (tiny)
__global__ __launch_bounds__(128) void scan_bsums(const int* __restrict__ bsum,
                                                  int* __restrict__ boff,
                                                  int* __restrict__ rowptr) {
    __shared__ int s[128];
    const int t = threadIdx.x;
    s[t] = (t < SNB) ? bsum[t] : 0;
    __syncthreads();
    for (int off = 1; off < 128; off <<= 1) {
        const int v = (t >= off) ? s[t - off] : 0;
        __syncthreads();
        s[t] += v;
        __syncthreads();
    }
    boff[t] = (t == 0) ? 0 : s[t - 1];
    if (t == 0) rowptr[NN] = s[SNB - 1];
}

// phase C: in-block exclusive scan + global offset -> rowptr & cursor
__global__ __launch_bounds__(256) void scan_fill(const int* __restrict__ deg,
                                                 const int* __restrict__ boff,
                                                 int* __restrict__ rowptr,
                                                 int* __restrict__ cursor) {
    const int t = threadIdx.x;
    const int base = blockIdx.x * SB + t * 4;
    int v[4], s = 0;
    #pragma unroll
    for (int k = 0; k < 4; ++k) {
        const int i = base + k;
        v[k] = (i < NN) ? deg[i] : 0;
        s += v[k];
    }
    __shared__ int red[256];
    red[t] = s;
    __syncthreads();
    for (int off = 1; off < 256; off <<= 1) {
        const int x = (t >= off) ? red[t - off] : 0;
        __syncthreads();
        red[t] += x;
        __syncthreads();
    }
    int run = boff[blockIdx.x] + ((t == 0) ? 0 : red[t - 1]);
    #pragma unroll
    for (int k = 0; k < 4; ++k) {
        const int i = base + k;
        if (i < NN) {
            rowptr[i] = run;
            cursor[i] = run;
            run += v[k];
        }
    }
}

__global__ __launch_bounds__(256) void csr_fill(const void* __restrict__ ei,
                                                int* __restrict__ cursor,
                                                int* __restrict__ col,
                                                const int* __restrict__ flag) {
    const bool is64 = (*flag != 0);
    const int i = blockIdx.x * blockDim.x + threadIdx.x;
    if (i < NE) {
        const int d = load_idx(ei, NE + i, is64);
        const int pos = atomicAdd(&cursor[d], 1);
        col[pos] = load_idx(ei, i, is64);
    }
}

// ---------------------------------------------------------------- gather aggregation: out[d] = x[d] + sum_{j->d} x[j]
template<int F>
__global__ __launch_bounds__(256) void gather_kernel(const float* __restrict__ x,
                                                     const int* __restrict__ rowptr,
                                                     const int* __restrict__ col,
                                                     float* __restrict__ out) {
    const int node = (blockIdx.x * blockDim.x + threadIdx.x) >> 6;
    const int lane = threadIdx.x & 63;
    if (node >= NN) return;
    const int beg = rowptr[node], end = rowptr[node + 1];
    if (F == 64) {
        float acc = x[node * 64 + lane];
        int e = beg;
        for (; e + 1 < end; e += 2) {
            const int s0 = col[e], s1 = col[e + 1];
            acc += x[s0 * 64 + lane] + x[s1 * 64 + lane];
        }
        if (e < end) acc += x[col[e] * 64 + lane];
        out[node * 64 + lane] = acc;
    } else {
        float2 acc = *(const float2*)&x[node * 128 + lane * 2];
        int e = beg;
        for (; e + 1 < end; e += 2) {
            const int s0 = col[e], s1 = col[e + 1];
            const float2 v0 = *(const float2*)&x[s0 * 128 + lane * 2];
            const float2 v1 = *(const float2*)&x[s1 * 128 + lane * 2];
            acc.x += v0.x + v1.x;
            acc.y += v0.y + v1.y;
        }
        if (e < end) {
            const float2 v = *(const float2*)&x[col[e] * 128 + lane * 2];
            acc.x += v.x; acc.y += v.y;
        }
        *(float2*)&out[node * 128 + lane * 2] = acc;
    }
}

// ---------------------------------------------------------------- C = M @ W + bias, fused BN column stats
// NOTE: M may alias C. Each block reads only its own 64 rows of M (LDS-staged,
// barriered) before the epilogue stores to those rows.
template<int FIN>
__global__ __launch_bounds__(256) void gemm_kernel(const float* M,
                                                   const float* __restrict__ W,
                                                   const float* __restrict__ bias,
                                                   float* C,
                                                   float* __restrict__ stats) {
    __shared__ float xs[64][33];
    __shared__ float ws[32][128];
    const int t = threadIdx.x;
    const int r0 = blockIdx.x * 64;
    const int ry = t >> 4, cx = t & 15, c0 = cx * 8;

    float acc[4][8];
    #pragma unroll
    for (int i = 0; i < 4; ++i)
        #pragma unroll
        for (int j = 0; j < 8; ++j) acc[i][j] = 0.f;

    for (int k0 = 0; k0 < FIN; k0 += 32) {
        {   // stage M tile (64 x 32)
            const int rr0 = t >> 3, kg = (t & 7) * 4;
            #pragma unroll
            for (int it = 0; it < 2; ++it) {
                const int rr = rr0 + it * 32;
                const int r = r0 + rr;
                float4 v = make_float4(0.f, 0.f, 0.f, 0.f);
                if (r < NN) v = *(const float4*)&M[r * FIN + k0 + kg];
                xs[rr][kg + 0] = v.x; xs[rr][kg + 1] = v.y;
                xs[rr][kg + 2] = v.z; xs[rr][kg + 3] = v.w;
            }
            // stage W tile (32 x 128)
            const int kk0 = t >> 5, cg = (t & 31) * 4;
            #pragma unroll
            for (int it = 0; it < 4; ++it) {
                const int kk = kk0 + it * 8;
                *(float4*)&ws[kk][cg] = *(const float4*)&W[(k0 + kk) * HID + cg];
            }
        }
        __syncthreads();
        #pragma unroll
        for (int k = 0; k < 32; ++k) {
            float xv[4], wv[8];
            #pragma unroll
            for (int i = 0; i < 4; ++i) xv[i] = xs[ry * 4 + i][k];
            *(float4*)&wv[0] = *(const float4*)&ws[k][c0];
            *(float4*)&wv[4] = *(const float4*)&ws[k][c0 + 4];
            #pragma unroll
            for (int i = 0; i < 4; ++i)
                #pragma unroll
                for (int j = 0; j < 8; ++j) acc[i][j] = fmaf(xv[i], wv[j], acc[i][j]);
        }
        __syncthreads();
    }
    // ---- epilogue: bias add, store, per-block BN partial stats
    float bv[8];
    *(float4*)&bv[0] = *(const float4*)&bias[c0];
    *(float4*)&bv[4] = *(const float4*)&bias[c0 + 4];
    float sc[8], qc[8];
    #pragma unroll
    for (int j = 0; j < 8; ++j) { sc[j] = 0.f; qc[j] = 0.f; }
    #pragma unroll
    for (int i = 0; i < 4; ++i) {
        const int r = r0 + ry * 4 + i;
        if (r < NN) {
            float o[8];
            #pragma unroll
            for (int j = 0; j < 8; ++j) {
                o[j] = acc[i][j] + bv[j];
                sc[j] += o[j];
                qc[j] = fmaf(o[j], o[j], qc[j]);
            }
            *(float4*)&C[r * HID + c0 + 0] = *(float4*)&o[0];
            *(float4*)&C[r * HID + c0 + 4] = *(float4*)&o[4];
        }
    }
    float* red = &ws[0][0];   // ws is dead after the final barrier; reuse 2048 floats
    #pragma unroll
    for (int j = 0; j < 8; ++j) red[ry * 128 + c0 + j] = sc[j];
    __syncthreads();
    if (t < 128) {
        float a = 0.f;
        #pragma unroll
        for (int k = 0; k < 16; ++k) a += red[k * 128 + t];
        unsafeAtomicAdd(&stats[t], a);
    }
    __syncthreads();
    #pragma unroll
    for (int j = 0; j < 8; ++j) red[ry * 128 + c0 + j] = qc[j];
    __syncthreads();
    if (t < 128) {
        float a = 0.f;
        #pragma unroll
        for (int k = 0; k < 16; ++k) a += red[k * 128 + t];
        unsafeAtomicAdd(&stats[128 + t], a);
    }
}

__global__ void bn_prep(const float* __restrict__ stats, const float* __restrict__ gamma,
                        const float* __restrict__ beta, float* __restrict__ coef) {
    const int c = threadIdx.x;  // 128
    const float inv_n = 1.f / (float)NN;
    const float mu = stats[c] * inv_n;
    const float var = stats[128 + c] * inv_n - mu * mu;
    const float a = gamma[c] * rsqrtf(var + BN_EPS);
    coef[c] = a;
    coef[128 + c] = fmaf(-mu, a, beta[c]);
}

__global__ __launch_bounds__(256) void bn_apply_relu(const float* __restrict__ C,
                                                     const float* __restrict__ coef,
                                                     float* __restrict__ out) {
    __shared__ float ca[128], cb[128];
    if (threadIdx.x < 128) {
        ca[threadIdx.x] = coef[threadIdx.x];
        cb[threadIdx.x] = coef[128 + threadIdx.x];
    }
    __syncthreads();
    const int total = NN * HID / 4;
    for (int i = blockIdx.x * blockDim.x + threadIdx.x; i < total; i += gridDim.x * blockDim.x) {
        float4 v = ((const float4*)C)[i];
        const int c0 = (i & 31) * 4;
        v.x = fmaxf(fmaf(v.x, ca[c0 + 0], cb[c0 + 0]), 0.f);
        v.y = fmaxf(fmaf(v.y, ca[c0 + 1], cb[c0 + 1]), 0.f);
        v.z = fmaxf(fmaf(v.z, ca[c0 + 2], cb[c0 + 2]), 0.f);
        v.w = fmaxf(fmaf(v.w, ca[c0 + 3], cb[c0 + 3]), 0.f);
        ((float4*)out)[i] = v;
    }
}

// ---------------------------------------------------------------- pool with fused BN+ReLU (layer 3)
__global__ __launch_bounds__(128) void pool_kernel(const float* __restrict__ x,
                                                   const void* __restrict__ batch,
                                                   const float* __restrict__ coef,
                                                   float* pooled, float* cnt,
                                                   const int* __restrict__ flag) {
    const bool is64 = (*flag != 0);
    const int c = threadIdx.x;  // 128
    const int rbeg = blockIdx.x * 512;
    if (rbeg >= NN) return;
    const int rend = min(rbeg + 512, NN);
    const float ca = coef[c], cb = coef[128 + c];
    int gprev = load_idx(batch, rbeg, is64);
    float acc = 0.f; int run = 0;
    for (int r = rbeg; r < rend; ++r) {
        const int g = load_idx(batch, r, is64);
        if (g != gprev) {
            unsafeAtomicAdd(&pooled[gprev * HID + c], acc);
            if (c == 0) unsafeAtomicAdd(&cnt[gprev], (float)run);
            acc = 0.f; run = 0; gprev = g;
        }
        acc += fmaxf(fmaf(x[r * HID + c], ca, cb), 0.f);
        ++run;
    }
    unsafeAtomicAdd(&pooled[gprev * HID + c], acc);
    if (c == 0) unsafeAtomicAdd(&cnt[gprev], (float)run);
}

__global__ __launch_bounds__(64) void pool_proj(const float* __restrict__ pooled,
                                                const float* __restrict__ cnt,
                                                const float* __restrict__ Wf,
                                                const float* __restrict__ bf,
                                                float* __restrict__ v) {
    const int g = blockIdx.x, c = threadIdx.x;  // 64
    const float inv = 1.f / fmaxf(cnt[g], 1.f);
    float acc = 0.f;
    for (int k = 0; k < HID; ++k) acc = fmaf(pooled[g * HID + k], Wf[k * EMB + c], acc);
    v[g * EMB + c] = fmaf(acc, inv, bf[c]);
}

// ---------------------------------------------------------------- classifier head
__global__ __launch_bounds__(256) void classifier(const float* __restrict__ v1,
                                                  const float* __restrict__ v2,
                                                  const float* __restrict__ Wc1,
                                                  const float* __restrict__ bc1,
                                                  const float* __restrict__ Wc2,
                                                  const float* __restrict__ bc2,
                                                  float* __restrict__ out) {
    const int g = threadIdx.x;
    if (g >= NG) return;
    float d[EMB];
    #pragma unroll
    for (int c = 0; c < EMB; ++c) d[c] = fabsf(v1[g * EMB + c] - v2[g * EMB + c]);
    float o = bc2[0];
    for (int j = 0; j < 32; ++j) {
        float h = bc1[j];
        #pragma unroll
        for (int c = 0; c < EMB; ++c) h = fmaf(d[c], Wc1[c * 32 + j], h);
        h = fmaxf(h, 0.f);
        o = fmaf(h, Wc2[j], o);
    }
    out[g] = 1.f / (1.f + expf(-o));
}

// ---------------------------------------------------------------- launch
extern "C" void kernel_launch(void* const* d_in, const int* in_sizes, int n_in,
                              void* d_out, int out_size, void* d_ws, size_t ws_size,
                              hipStream_t stream) {
    const float* x1 = (const float*)d_in[0];
    const float* x2 = (const float*)d_in[1];
    const void* ei1 = d_in[2];
    const void* ei2 = d_in[3];
    const void* bt1 = d_in[4];
    const void* bt2 = d_in[5];
    const float* W[3]  = {(const float*)d_in[6],  (const float*)d_in[10], (const float*)d_in[14]};
    const float* bb[3] = {(const float*)d_in[7],  (const float*)d_in[11], (const float*)d_in[15]};
    const float* gg[3] = {(const float*)d_in[8],  (const float*)d_in[12], (const float*)d_in[16]};
    const float* be[3] = {(const float*)d_in[9],  (const float*)d_in[13], (const float*)d_in[17]};
    const float* Wf  = (const float*)d_in[18];
    const float* bfv = (const float*)d_in[19];
    const float* Wc1 = (const float*)d_in[20];
    const float* bc1 = (const float*)d_in[21];
    const float* Wc2 = (const float*)d_in[22];
    const float* bc2 = (const float*)d_in[23];

    float* A  = (float*)d_ws;                 // N x 128 activations
    float* B  = A + (size_t)NN * HID;         // N x 128 aggregation / GEMM out
    float* SM = B + (size_t)NN * HID;         // small region
    int*   flag   = (int*)SM;                 // [16]
    float* stats  = SM + 16;                  // 6 x 512 (sum,sumsq | coefA,coefB)
    float* pooled = stats + 6 * 512;          // 2 x G x 128
    float* cnt    = pooled + 2 * NG * HID;    // 2 x G
    float* vv     = cnt + 2 * NG;             // 2 x G x 64
    // CSR region (rebuilt per side)
    int* deg    = (int*)(vv + 2 * NG * EMB);  // NN
    int* rowptr = deg + NN;                   // NN+1
    int* cursor = rowptr + NN + 1;            // NN
    int* bsum   = cursor + NN;                // 128
    int* boff   = bsum + 128;                 // 128
    int* col    = boff + 128;                 // NE

    hipMemsetAsync(SM, 0, (size_t)(16 + 6 * 512 + 2 * NG * HID + 2 * NG) * sizeof(float), stream);
    detect_i64_kernel<<<1, 64, 0, stream>>>(ei1, flag);

    const int EB = (NE + 255) / 256;          // edge-parallel blocks
    const int GB = (NN * 64) / 256;           // wave-per-node blocks (25000)

    for (int side = 0; side < 2; ++side) {
        const float* x0 = side ? x2 : x1;
        const void* ei  = side ? ei2 : ei1;
        const void* bt  = side ? bt2 : bt1;
        float* ppool = pooled + side * NG * HID;
        float* pcnt  = cnt + side * NG;
        float* pv    = vv + side * NG * EMB;

        // ---- build dst-CSR (parallel 3-phase scan)
        hipMemsetAsync(deg, 0, (size_t)NN * sizeof(int), stream);
        csr_hist<<<EB, 256, 0, stream>>>(ei, deg, flag);
        scan_block_sums<<<SNB, 256, 0, stream>>>(deg, bsum);
        scan_bsums<<<1, 128, 0, stream>>>(bsum, boff, rowptr);
        scan_fill<<<SNB, 256, 0, stream>>>(deg, boff, rowptr, cursor);
        csr_fill<<<EB, 256, 0, stream>>>(ei, cursor, col, flag);

        float* st0 = stats + (side * 3 + 0) * 512;
        float* st1 = stats + (side * 3 + 1) * 512;
        float* st2 = stats + (side * 3 + 2) * 512;

        // ---- layer 1 (FIN=64)
        gather_kernel<64><<<GB, 256, 0, stream>>>(x0, rowptr, col, B);
        gemm_kernel<64><<<(NN + 63) / 64, 256, 0, stream>>>(B, W[0], bb[0], A, st0);
        bn_prep<<<1, 128, 0, stream>>>(st0, gg[0], be[0], st0 + 256);
        bn_apply_relu<<<2048, 256, 0, stream>>>(A, st0 + 256, A);
        // ---- layer 2
        gather_kernel<128><<<GB, 256, 0, stream>>>(A, rowptr, col, B);
        gemm_kernel<128><<<(NN + 63) / 64, 256, 0, stream>>>(B, W[1], bb[1], B, st1);
        bn_prep<<<1, 128, 0, stream>>>(st1, gg[1], be[1], st1 + 256);
        bn_apply_relu<<<2048, 256, 0, stream>>>(B, st1 + 256, A);
        // ---- layer 3: BN+ReLU fused into pool
        gather_kernel<128><<<GB, 256, 0, stream>>>(A, rowptr, col, B);
        gemm_kernel<128><<<(NN + 63) / 64, 256, 0, stream>>>(B, W[2], bb[2], B, st2);
        bn_prep<<<1, 128, 0, stream>>>(st2, gg[2], be[2], st2 + 256);
        pool_kernel<<<(NN + 511) / 512, 128, 0, stream>>>(B, bt, st2 + 256, ppool, pcnt, flag);
        pool_proj<<<NG, 64, 0, stream>>>(ppool, pcnt, Wf, bfv, pv);
    }
    classifier<<<1, 256, 0, stream>>>(vv, vv + NG * EMB, Wc1, bc1, Wc2, bc2, (float*)d_out);
}

// Round 4
// 1434.704 us; speedup vs baseline: 4.0868x; 1.2807x over previous
//
#include <hip/hip_runtime.h>
#include <hip/hip_bf16.h>
#include <math.h>

#define NN 100000
#define NE 1280000
#define NG 256
#define HID 128
#define EMB 64
#define BN_EPS 1e-5f
#define SB 1024
#define SNB ((NN + SB - 1) / SB)   // 98

// ---------------------------------------------------------------- utilities
__global__ void detect_i64_kernel(const void* __restrict__ ei, int* __restrict__ flag) {
    if (threadIdx.x == 0 && blockIdx.x == 0) {
        // int32 pairs read as u64 -> hi word ~U[0,100000) -> almost surely >= 2^32 somewhere.
        const unsigned long long* p = (const unsigned long long*)ei;
        int is64 = 1;
        #pragma unroll
        for (int i = 0; i < 16; ++i)
            if (p[i] >= (1ull << 32)) is64 = 0;
        *flag = is64;
    }
}

__device__ __forceinline__ int load_idx(const void* p, int i, bool is64) {
    return is64 ? (int)((const long long*)p)[i] : ((const int*)p)[i];
}

// ---------------------------------------------------------------- CSR build (dst-sorted)
__global__ __launch_bounds__(256) void csr_hist(const void* __restrict__ ei,
                                                int* __restrict__ deg,
                                                const int* __restrict__ flag) {
    const bool is64 = (*flag != 0);
    const int i = blockIdx.x * blockDim.x + threadIdx.x;
    if (i < NE) atomicAdd(&deg[load_idx(ei, NE + i, is64)], 1);
}

__global__ __launch_bounds__(256) void scan_block_sums(const int* __restrict__ deg,
                                                       int* __restrict__ bsum) {
    const int t = threadIdx.x;
    const int base = blockIdx.x * SB + t * 4;
    int s = 0;
    #pragma unroll
    for (int k = 0; k < 4; ++k) {
        const int i = base + k;
        if (i < NN) s += deg[i];
    }
    __shared__ int red[256];
    red[t] = s;
    __syncthreads();
    for (int off = 128; off > 0; off >>= 1) {
        if (t < off) red[t] += red[t + off];
        __syncthreads();
    }
    if (t == 0) bsum[blockIdx.x] = red[0];
}

__global__ __launch_bounds__(128) void scan_bsums(const int* __restrict__ bsum,
                                                  int* __restrict__ boff,
                                                  int* __restrict__ rowptr) {
    __shared__ int s[128];
    const int t = threadIdx.x;
    s[t] = (t < SNB) ? bsum[t] : 0;
    __syncthreads();
    for (int off = 1; off < 128; off <<= 1) {
        const int v = (t >= off) ? s[t - off] : 0;
        __syncthreads();
        s[t] += v;
        __syncthreads();
    }
    boff[t] = (t == 0) ? 0 : s[t - 1];
    if (t == 0) rowptr[NN] = s[SNB - 1];
}

__global__ __launch_bounds__(256) void scan_fill(const int* __restrict__ deg,
                                                 const int* __restrict__ boff,
                                                 int* __restrict__ rowptr,
                                                 int* __restrict__ cursor) {
    const int t = threadIdx.x;
    const int base = blockIdx.x * SB + t * 4;
    int v[4], s = 0;
    #pragma unroll
    for (int k = 0; k < 4; ++k) {
        const int i = base + k;
        v[k] = (i < NN) ? deg[i] : 0;
        s += v[k];
    }
    __shared__ int red[256];
    red[t] = s;
    __syncthreads();
    for (int off = 1; off < 256; off <<= 1) {
        const int x = (t >= off) ? red[t - off] : 0;
        __syncthreads();
        red[t] += x;
        __syncthreads();
    }
    int run = boff[blockIdx.x] + ((t == 0) ? 0 : red[t - 1]);
    #pragma unroll
    for (int k = 0; k < 4; ++k) {
        const int i = base + k;
        if (i < NN) {
            rowptr[i] = run;
            cursor[i] = run;
            run += v[k];
        }
    }
}

__global__ __launch_bounds__(256) void csr_fill(const void* __restrict__ ei,
                                                int* __restrict__ cursor,
                                                int* __restrict__ col,
                                                const int* __restrict__ flag) {
    const bool is64 = (*flag != 0);
    const int i = blockIdx.x * blockDim.x + threadIdx.x;
    if (i < NE) {
        const int d = load_idx(ei, NE + i, is64);
        const int pos = atomicAdd(&cursor[d], 1);
        col[pos] = load_idx(ei, i, is64);
    }
}

// ---------------------------------------------------------------- gather aggregation
// out[d] = f(x[d]) + sum_{j->d} f(x[j]),  f = BN ? relu(a*v+b) : identity
template<int F, bool BN>
__global__ __launch_bounds__(256) void gather_kernel(const float* __restrict__ x,
                                                     const int* __restrict__ rowptr,
                                                     const int* __restrict__ col,
                                                     const float* __restrict__ coef,
                                                     float* __restrict__ out) {
    const int node = (blockIdx.x * blockDim.x + threadIdx.x) >> 6;
    const int lane = threadIdx.x & 63;
    if (node >= NN) return;
    const int beg = rowptr[node], end = rowptr[node + 1];
    if (F == 64) {
        float acc = x[node * 64 + lane];
        int e = beg;
        for (; e + 3 < end; e += 4) {
            const int s0 = col[e], s1 = col[e + 1], s2 = col[e + 2], s3 = col[e + 3];
            acc += x[s0 * 64 + lane] + x[s1 * 64 + lane]
                 + x[s2 * 64 + lane] + x[s3 * 64 + lane];
        }
        for (; e < end; ++e) acc += x[col[e] * 64 + lane];
        out[node * 64 + lane] = acc;
    } else {
        float2 ca, cb;
        if (BN) {
            ca = *(const float2*)&coef[lane * 2];
            cb = *(const float2*)&coef[128 + lane * 2];
        }
        float2 v0 = *(const float2*)&x[node * 128 + lane * 2];
        float2 acc;
        if (BN) {
            acc.x = fmaxf(fmaf(v0.x, ca.x, cb.x), 0.f);
            acc.y = fmaxf(fmaf(v0.y, ca.y, cb.y), 0.f);
        } else acc = v0;
        int e = beg;
        for (; e + 3 < end; e += 4) {
            const int s0 = col[e], s1 = col[e + 1], s2 = col[e + 2], s3 = col[e + 3];
            float2 a = *(const float2*)&x[s0 * 128 + lane * 2];
            float2 b = *(const float2*)&x[s1 * 128 + lane * 2];
            float2 c = *(const float2*)&x[s2 * 128 + lane * 2];
            float2 d = *(const float2*)&x[s3 * 128 + lane * 2];
            if (BN) {
                acc.x += fmaxf(fmaf(a.x, ca.x, cb.x), 0.f) + fmaxf(fmaf(b.x, ca.x, cb.x), 0.f)
                       + fmaxf(fmaf(c.x, ca.x, cb.x), 0.f) + fmaxf(fmaf(d.x, ca.x, cb.x), 0.f);
                acc.y += fmaxf(fmaf(a.y, ca.y, cb.y), 0.f) + fmaxf(fmaf(b.y, ca.y, cb.y), 0.f)
                       + fmaxf(fmaf(c.y, ca.y, cb.y), 0.f) + fmaxf(fmaf(d.y, ca.y, cb.y), 0.f);
            } else {
                acc.x += a.x + b.x + c.x + d.x;
                acc.y += a.y + b.y + c.y + d.y;
            }
        }
        for (; e < end; ++e) {
            const float2 v = *(const float2*)&x[col[e] * 128 + lane * 2];
            if (BN) {
                acc.x += fmaxf(fmaf(v.x, ca.x, cb.x), 0.f);
                acc.y += fmaxf(fmaf(v.y, ca.y, cb.y), 0.f);
            } else {
                acc.x += v.x; acc.y += v.y;
            }
        }
        *(float2*)&out[node * 128 + lane * 2] = acc;
    }
}

// ---------------------------------------------------------------- C = M @ W + bias, fused BN column stats
// NOTE: M may alias C. Each block reads only its own 64 rows of M (LDS-staged,
// barriered each k-chunk) and stores those rows only in the epilogue, after all
// its reads; no other block touches them.
template<int FIN>
__global__ __launch_bounds__(256) void gemm_kernel(const float* M,
                                                   const float* __restrict__ W,
                                                   const float* __restrict__ bias,
                                                   float* C,
                                                   float* __restrict__ stats) {
    __shared__ float xs[64][33];
    __shared__ float ws[32][128];
    const int t = threadIdx.x;
    const int r0 = blockIdx.x * 64;
    const int ry = t >> 4, cx = t & 15, c0 = cx * 8;

    float acc[4][8];
    #pragma unroll
    for (int i = 0; i < 4; ++i)
        #pragma unroll
        for (int j = 0; j < 8; ++j) acc[i][j] = 0.f;

    for (int k0 = 0; k0 < FIN; k0 += 32) {
        {   // stage M tile (64 x 32)
            const int rr0 = t >> 3, kg = (t & 7) * 4;
            #pragma unroll
            for (int it = 0; it < 2; ++it) {
                const int rr = rr0 + it * 32;
                const int r = r0 + rr;
                float4 v = make_float4(0.f, 0.f, 0.f, 0.f);
                if (r < NN) v = *(const float4*)&M[r * FIN + k0 + kg];
                xs[rr][kg + 0] = v.x; xs[rr][kg + 1] = v.y;
                xs[rr][kg + 2] = v.z; xs[rr][kg + 3] = v.w;
            }
            // stage W tile (32 x 128)
            const int kk0 = t >> 5, cg = (t & 31) * 4;
            #pragma unroll
            for (int it = 0; it < 4; ++it) {
                const int kk = kk0 + it * 8;
                *(float4*)&ws[kk][cg] = *(const float4*)&W[(k0 + kk) * HID + cg];
            }
        }
        __syncthreads();
        #pragma unroll
        for (int k = 0; k < 32; ++k) {
            float xv[4], wv[8];
            #pragma unroll
            for (int i = 0; i < 4; ++i) xv[i] = xs[ry * 4 + i][k];
            *(float4*)&wv[0] = *(const float4*)&ws[k][c0];
            *(float4*)&wv[4] = *(const float4*)&ws[k][c0 + 4];
            #pragma unroll
            for (int i = 0; i < 4; ++i)
                #pragma unroll
                for (int j = 0; j < 8; ++j) acc[i][j] = fmaf(xv[i], wv[j], acc[i][j]);
        }
        __syncthreads();
    }
    // ---- epilogue: bias add, store, per-block BN partial stats
    float bv[8];
    *(float4*)&bv[0] = *(const float4*)&bias[c0];
    *(float4*)&bv[4] = *(const float4*)&bias[c0 + 4];
    float sc[8], qc[8];
    #pragma unroll
    for (int j = 0; j < 8; ++j) { sc[j] = 0.f; qc[j] = 0.f; }
    #pragma unroll
    for (int i = 0; i < 4; ++i) {
        const int r = r0 + ry * 4 + i;
        if (r < NN) {
            float o[8];
            #pragma unroll
            for (int j = 0; j < 8; ++j) {
                o[j] = acc[i][j] + bv[j];
                sc[j] += o[j];
                qc[j] = fmaf(o[j], o[j], qc[j]);
            }
            *(float4*)&C[r * HID + c0 + 0] = *(float4*)&o[0];
            *(float4*)&C[r * HID + c0 + 4] = *(float4*)&o[4];
        }
    }
    float* red = &ws[0][0];   // ws dead after final barrier; 2048 floats
    #pragma unroll
    for (int j = 0; j < 8; ++j) red[ry * 128 + c0 + j] = sc[j];
    __syncthreads();
    if (t < 128) {
        float a = 0.f;
        #pragma unroll
        for (int k = 0; k < 16; ++k) a += red[k * 128 + t];
        unsafeAtomicAdd(&stats[t], a);
    }
    __syncthreads();
    #pragma unroll
    for (int j = 0; j < 8; ++j) red[ry * 128 + c0 + j] = qc[j];
    __syncthreads();
    if (t < 128) {
        float a = 0.f;
        #pragma unroll
        for (int k = 0; k < 16; ++k) a += red[k * 128 + t];
        unsafeAtomicAdd(&stats[128 + t], a);
    }
}

__global__ void bn_prep(const float* __restrict__ stats, const float* __restrict__ gamma,
                        const float* __restrict__ beta, float* __restrict__ coef) {
    const int c = threadIdx.x;  // 128
    const float inv_n = 1.f / (float)NN;
    const float mu = stats[c] * inv_n;
    const float var = stats[128 + c] * inv_n - mu * mu;
    const float a = gamma[c] * rsqrtf(var + BN_EPS);
    coef[c] = a;
    coef[128 + c] = fmaf(-mu, a, beta[c]);
}

// ---------------------------------------------------------------- pool with fused BN+ReLU (layer 3)
// 64 rows per block; fast path when the chunk lies in a single group (avg run = 390 rows)
__global__ __launch_bounds__(128) void pool_kernel(const float* __restrict__ x,
                                                   const void* __restrict__ batch,
                                                   const float* __restrict__ coef,
                                                   float* pooled, float* cnt,
                                                   const int* __restrict__ flag) {
    const bool is64 = (*flag != 0);
    const int c = threadIdx.x;  // 128
    const int rbeg = blockIdx.x * 64;
    if (rbeg >= NN) return;
    const int rend = min(rbeg + 64, NN);
    const float ca = coef[c], cb = coef[128 + c];
    const int g0 = load_idx(batch, rbeg, is64);
    const int g1 = load_idx(batch, rend - 1, is64);
    if (g0 == g1) {
        float acc = 0.f;
        #pragma unroll 8
        for (int r = rbeg; r < rend; ++r)
            acc += fmaxf(fmaf(x[r * HID + c], ca, cb), 0.f);
        unsafeAtomicAdd(&pooled[g0 * HID + c], acc);
        if (c == 0) unsafeAtomicAdd(&cnt[g0], (float)(rend - rbeg));
        return;
    }
    int gprev = g0;
    float acc = 0.f; int run = 0;
    for (int r = rbeg; r < rend; ++r) {
        const int g = load_idx(batch, r, is64);
        if (g != gprev) {
            unsafeAtomicAdd(&pooled[gprev * HID + c], acc);
            if (c == 0) unsafeAtomicAdd(&cnt[gprev], (float)run);
            acc = 0.f; run = 0; gprev = g;
        }
        acc += fmaxf(fmaf(x[r * HID + c], ca, cb), 0.f);
        ++run;
    }
    unsafeAtomicAdd(&pooled[gprev * HID + c], acc);
    if (c == 0) unsafeAtomicAdd(&cnt[gprev], (float)run);
}

__global__ __launch_bounds__(64) void pool_proj(const float* __restrict__ pooled,
                                                const float* __restrict__ cnt,
                                                const float* __restrict__ Wf,
                                                const float* __restrict__ bf,
                                                float* __restrict__ v) {
    const int g = blockIdx.x, c = threadIdx.x;  // 64
    const float inv = 1.f / fmaxf(cnt[g], 1.f);
    float acc = 0.f;
    for (int k = 0; k < HID; ++k) acc = fmaf(pooled[g * HID + k], Wf[k * EMB + c], acc);
    v[g * EMB + c] = fmaf(acc, inv, bf[c]);
}

// ---------------------------------------------------------------- classifier head
__global__ __launch_bounds__(256) void classifier(const float* __restrict__ v1,
                                                  const float* __restrict__ v2,
                                                  const float* __restrict__ Wc1,
                                                  const float* __restrict__ bc1,
                                                  const float* __restrict__ Wc2,
                                                  const float* __restrict__ bc2,
                                                  float* __restrict__ out) {
    const int g = threadIdx.x;
    if (g >= NG) return;
    float d[EMB];
    #pragma unroll
    for (int c = 0; c < EMB; ++c) d[c] = fabsf(v1[g * EMB + c] - v2[g * EMB + c]);
    float o = bc2[0];
    for (int j = 0; j < 32; ++j) {
        float h = bc1[j];
        #pragma unroll
        for (int c = 0; c < EMB; ++c) h = fmaf(d[c], Wc1[c * 32 + j], h);
        h = fmaxf(h, 0.f);
        o = fmaf(h, Wc2[j], o);
    }
    out[g] = 1.f / (1.f + expf(-o));
}

// ---------------------------------------------------------------- launch
extern "C" void kernel_launch(void* const* d_in, const int* in_sizes, int n_in,
                              void* d_out, int out_size, void* d_ws, size_t ws_size,
                              hipStream_t stream) {
    const float* x1 = (const float*)d_in[0];
    const float* x2 = (const float*)d_in[1];
    const void* ei1 = d_in[2];
    const void* ei2 = d_in[3];
    const void* bt1 = d_in[4];
    const void* bt2 = d_in[5];
    const float* W[3]  = {(const float*)d_in[6],  (const float*)d_in[10], (const float*)d_in[14]};
    const float* bb[3] = {(const float*)d_in[7],  (const float*)d_in[11], (const float*)d_in[15]};
    const float* gg[3] = {(const float*)d_in[8],  (const float*)d_in[12], (const float*)d_in[16]};
    const float* be[3] = {(const float*)d_in[9],  (const float*)d_in[13], (const float*)d_in[17]};
    const float* Wf  = (const float*)d_in[18];
    const float* bfv = (const float*)d_in[19];
    const float* Wc1 = (const float*)d_in[20];
    const float* bc1 = (const float*)d_in[21];
    const float* Wc2 = (const float*)d_in[22];
    const float* bc2 = (const float*)d_in[23];

    float* A  = (float*)d_ws;                 // N x 128
    float* B  = A + (size_t)NN * HID;         // N x 128
    float* SM = B + (size_t)NN * HID;
    int*   flag   = (int*)SM;                 // [16]
    float* stats  = SM + 16;                  // 6 x 512 (sum,sumsq | coefA,coefB)
    float* pooled = stats + 6 * 512;          // 2 x G x 128
    float* cnt    = pooled + 2 * NG * HID;    // 2 x G
    float* vv     = cnt + 2 * NG;             // 2 x G x 64
    int* deg    = (int*)(vv + 2 * NG * EMB);  // NN
    int* rowptr = deg + NN;                   // NN+1
    int* cursor = rowptr + NN + 1;            // NN
    int* bsum   = cursor + NN;                // 128
    int* boff   = bsum + 128;                 // 128
    int* col    = boff + 128;                 // NE

    hipMemsetAsync(SM, 0, (size_t)(16 + 6 * 512 + 2 * NG * HID + 2 * NG) * sizeof(float), stream);
    detect_i64_kernel<<<1, 64, 0, stream>>>(ei1, flag);

    const int EB = (NE + 255) / 256;
    const int GB = (NN * 64) / 256;           // wave-per-node blocks (25000)

    for (int side = 0; side < 2; ++side) {
        const float* x0 = side ? x2 : x1;
        const void* ei  = side ? ei2 : ei1;
        const void* bt  = side ? bt2 : bt1;
        float* ppool = pooled + side * NG * HID;
        float* pcnt  = cnt + side * NG;
        float* pv    = vv + side * NG * EMB;

        // ---- build dst-CSR (parallel 3-phase scan)
        hipMemsetAsync(deg, 0, (size_t)NN * sizeof(int), stream);
        csr_hist<<<EB, 256, 0, stream>>>(ei, deg, flag);
        scan_block_sums<<<SNB, 256, 0, stream>>>(deg, bsum);
        scan_bsums<<<1, 128, 0, stream>>>(bsum, boff, rowptr);
        scan_fill<<<SNB, 256, 0, stream>>>(deg, boff, rowptr, cursor);
        csr_fill<<<EB, 256, 0, stream>>>(ei, cursor, col, flag);

        float* st0 = stats + (side * 3 + 0) * 512;
        float* st1 = stats + (side * 3 + 1) * 512;
        float* st2 = stats + (side * 3 + 2) * 512;

        // ---- layer 1: B = agg(x0); A = h1
        gather_kernel<64, false><<<GB, 256, 0, stream>>>(x0, rowptr, col, nullptr, B);
        gemm_kernel<64><<<(NN + 63) / 64, 256, 0, stream>>>(B, W[0], bb[0], A, st0);
        bn_prep<<<1, 128, 0, stream>>>(st0, gg[0], be[0], st0 + 256);
        // ---- layer 2: B = agg(relu(bn(h1))); B = h2 (in-place)
        gather_kernel<128, true><<<GB, 256, 0, stream>>>(A, rowptr, col, st0 + 256, B);
        gemm_kernel<128><<<(NN + 63) / 64, 256, 0, stream>>>(B, W[1], bb[1], B, st1);
        bn_prep<<<1, 128, 0, stream>>>(st1, gg[1], be[1], st1 + 256);
        // ---- layer 3: A = agg(relu(bn(h2))); A = h3 (in-place)
        gather_kernel<128, true><<<GB, 256, 0, stream>>>(B, rowptr, col, st1 + 256, A);
        gemm_kernel<128><<<(NN + 63) / 64, 256, 0, stream>>>(A, W[2], bb[2], A, st2);
        bn_prep<<<1, 128, 0, stream>>>(st2, gg[2], be[2], st2 + 256);
        // ---- pool applies relu(bn(h3)) on the fly
        pool_kernel<<<(NN + 63) / 64, 128, 0, stream>>>(A, bt, st2 + 256, ppool, pcnt, flag);
        pool_proj<<<NG, 64, 0, stream>>>(ppool, pcnt, Wf, bfv, pv);
    }
    classifier<<<1, 256, 0, stream>>>(vv, vv + NG * EMB, Wc1, bc1, Wc2, bc2, (float*)d_out);
}

// Round 5
// 1198.976 us; speedup vs baseline: 4.8902x; 1.1966x over previous
//
#include <hip/hip_runtime.h>
#include <hip/hip_bf16.h>
#include <math.h>

#define NN 100000
#define NE 1280000
#define NG 256
#define HID 128
#define EMB 64
#define BN_EPS 1e-5f
#define SB 1024
#define SNB ((NN + SB - 1) / SB)   // 98
#define GBLK 25000                 // gather blocks per side (4 nodes/block)
#define NBG 1563                   // gemm/pool blocks per side (64 rows/block)

// ---------------------------------------------------------------- bf16 helpers (manual, RNE)
__device__ __forceinline__ float bf2f(unsigned int u) { return __uint_as_float(u << 16); }
__device__ __forceinline__ unsigned int f2b(float f) {
    unsigned int u = __float_as_uint(f);
    return (u + 0x7fffu + ((u >> 16) & 1u)) >> 16;
}

// ---------------------------------------------------------------- utilities
__global__ void detect_i64_kernel(const void* __restrict__ ei, int* __restrict__ flag) {
    if (threadIdx.x == 0 && blockIdx.x == 0) {
        // int32 pairs read as u64 -> hi word ~U[0,100000) -> almost surely >= 2^32 somewhere.
        const unsigned long long* p = (const unsigned long long*)ei;
        int is64 = 1;
        #pragma unroll
        for (int i = 0; i < 16; ++i)
            if (p[i] >= (1ull << 32)) is64 = 0;
        *flag = is64;
    }
}

__device__ __forceinline__ int load_idx(const void* p, int i, bool is64) {
    return is64 ? (int)((const long long*)p)[i] : ((const int*)p)[i];
}

// ---------------------------------------------------------------- x -> bf16 (both sides, one pass)
__global__ __launch_bounds__(256) void convert_x(const float* __restrict__ x1,
                                                 const float* __restrict__ x2,
                                                 ushort* __restrict__ o1,
                                                 ushort* __restrict__ o2) {
    const int per = NN * 16;  // float4s per side
    const int i = blockIdx.x * 256 + threadIdx.x;   // grid covers exactly 2*per
    const int side = i >= per;
    const int j = i - side * per;
    const float4 v = ((const float4*)(side ? x2 : x1))[j];
    ushort4 o;
    o.x = (ushort)f2b(v.x); o.y = (ushort)f2b(v.y);
    o.z = (ushort)f2b(v.z); o.w = (ushort)f2b(v.w);
    ((ushort4*)(side ? o2 : o1))[j] = o;
}

// ---------------------------------------------------------------- CSR build, both sides fused
__global__ __launch_bounds__(256) void csr_hist2(const void* __restrict__ e1,
                                                 const void* __restrict__ e2,
                                                 int* __restrict__ degA,
                                                 int* __restrict__ degB,
                                                 const int* __restrict__ flag) {
    const bool is64 = (*flag != 0);
    const int i = blockIdx.x * 256 + threadIdx.x;
    if (i < 2 * NE) {
        const int side = i >= NE;
        const int j = i - side * NE;
        atomicAdd(&(side ? degB : degA)[load_idx(side ? e2 : e1, NE + j, is64)], 1);
    }
}

__global__ __launch_bounds__(256) void scan_block_sums2(const int* __restrict__ degA,
                                                        const int* __restrict__ degB,
                                                        int* __restrict__ bsum) {
    const int side = blockIdx.x >= SNB;
    const int bx = blockIdx.x - side * SNB;
    const int* deg = side ? degB : degA;
    const int t = threadIdx.x;
    const int base = bx * SB + t * 4;
    int s = 0;
    #pragma unroll
    for (int k = 0; k < 4; ++k) {
        const int i = base + k;
        if (i < NN) s += deg[i];
    }
    __shared__ int red[256];
    red[t] = s;
    __syncthreads();
    for (int off = 128; off > 0; off >>= 1) {
        if (t < off) red[t] += red[t + off];
        __syncthreads();
    }
    if (t == 0) bsum[side * 128 + bx] = red[0];
}

__global__ __launch_bounds__(128) void scan_bsums2(const int* __restrict__ bsum,
                                                   int* __restrict__ boff,
                                                   int* __restrict__ rpA,
                                                   int* __restrict__ rpB) {
    const int side = blockIdx.x;
    __shared__ int s[128];
    const int t = threadIdx.x;
    s[t] = (t < SNB) ? bsum[side * 128 + t] : 0;
    __syncthreads();
    for (int off = 1; off < 128; off <<= 1) {
        const int v = (t >= off) ? s[t - off] : 0;
        __syncthreads();
        s[t] += v;
        __syncthreads();
    }
    boff[side * 128 + t] = (t == 0) ? 0 : s[t - 1];
    if (t == 0) (side ? rpB : rpA)[NN] = s[SNB - 1];
}

__global__ __launch_bounds__(256) void scan_fill2(const int* __restrict__ degA,
                                                  const int* __restrict__ degB,
                                                  const int* __restrict__ boff,
                                                  int* __restrict__ rpA,
                                                  int* __restrict__ rpB,
                                                  int* __restrict__ curA,
                                                  int* __restrict__ curB) {
    const int side = blockIdx.x >= SNB;
    const int bx = blockIdx.x - side * SNB;
    const int* deg = side ? degB : degA;
    int* rowptr = side ? rpB : rpA;
    int* cursor = side ? curB : curA;
    const int t = threadIdx.x;
    const int base = bx * SB + t * 4;
    int v[4], s = 0;
    #pragma unroll
    for (int k = 0; k < 4; ++k) {
        const int i = base + k;
        v[k] = (i < NN) ? deg[i] : 0;
        s += v[k];
    }
    __shared__ int red[256];
    red[t] = s;
    __syncthreads();
    for (int off = 1; off < 256; off <<= 1) {
        const int x = (t >= off) ? red[t - off] : 0;
        __syncthreads();
        red[t] += x;
        __syncthreads();
    }
    int run = boff[side * 128 + bx] + ((t == 0) ? 0 : red[t - 1]);
    #pragma unroll
    for (int k = 0; k < 4; ++k) {
        const int i = base + k;
        if (i < NN) {
            rowptr[i] = run;
            cursor[i] = run;
            run += v[k];
        }
    }
}

__global__ __launch_bounds__(256) void csr_fill2(const void* __restrict__ e1,
                                                 const void* __restrict__ e2,
                                                 int* __restrict__ curA,
                                                 int* __restrict__ curB,
                                                 int* __restrict__ colA,
                                                 int* __restrict__ colB,
                                                 const int* __restrict__ flag) {
    const bool is64 = (*flag != 0);
    const int i = blockIdx.x * 256 + threadIdx.x;
    if (i < 2 * NE) {
        const int side = i >= NE;
        const int j = i - side * NE;
        const void* e = side ? e2 : e1;
        const int d = load_idx(e, NE + j, is64);
        const int pos = atomicAdd(&(side ? curB : curA)[d], 1);
        (side ? colB : colA)[pos] = load_idx(e, j, is64);
    }
}

// ---------------------------------------------------------------- gather (bf16 in/out, fp32 accum)
// out[d] = f(x[d]) + sum_{j->d} f(x[j]);  f = BN ? relu(a*v+b) : identity (coefs from raw stats)
struct GatherArgs {
    const ushort *xA, *xB;
    const int *rpA, *rpB, *colA, *colB;
    const float *stA, *stB;        // raw (sum[128], sumsq[128]) or null
    const float *gamma, *beta;     // shared (siamese)
    ushort *oA, *oB;
};

template<int F, bool BN>
__global__ __launch_bounds__(256) void gather16(GatherArgs a) {
    const int side = blockIdx.x >= GBLK;
    const int bx = blockIdx.x - side * GBLK;
    const ushort* __restrict__ x = side ? a.xB : a.xA;
    const int* __restrict__ rowptr = side ? a.rpB : a.rpA;
    const int* __restrict__ col = side ? a.colB : a.colA;
    ushort* __restrict__ out = side ? a.oB : a.oA;

    const int node = (bx * 256 + threadIdx.x) >> 6;
    const int lane = threadIdx.x & 63;
    if (node >= NN) return;
    const int beg = rowptr[node], end = rowptr[node + 1];

    if (F == 64) {
        float acc = bf2f(x[node * 64 + lane]);
        int e = beg;
        for (; e + 3 < end; e += 4) {
            const int s0 = col[e], s1 = col[e + 1], s2 = col[e + 2], s3 = col[e + 3];
            acc += bf2f(x[s0 * 64 + lane]) + bf2f(x[s1 * 64 + lane])
                 + bf2f(x[s2 * 64 + lane]) + bf2f(x[s3 * 64 + lane]);
        }
        for (; e < end; ++e) acc += bf2f(x[col[e] * 64 + lane]);
        out[node * 64 + lane] = (ushort)f2b(acc);
    } else {
        float cax = 1.f, cay = 1.f, cbx = 0.f, cby = 0.f;
        if (BN) {
            const float* st = side ? a.stB : a.stA;
            const int c0 = lane * 2, c1 = c0 + 1;
            const float inv_n = 1.f / (float)NN;
            const float mu0 = st[c0] * inv_n, mu1 = st[c1] * inv_n;
            const float v0 = st[128 + c0] * inv_n - mu0 * mu0;
            const float v1 = st[128 + c1] * inv_n - mu1 * mu1;
            cax = a.gamma[c0] * rsqrtf(v0 + BN_EPS);
            cay = a.gamma[c1] * rsqrtf(v1 + BN_EPS);
            cbx = fmaf(-mu0, cax, a.beta[c0]);
            cby = fmaf(-mu1, cay, a.beta[c1]);
        }
        #define LD(s) (*(const unsigned int*)&x[(s) * 128 + lane * 2])
        #define FX(u) (BN ? fmaxf(fmaf(bf2f((u) & 0xffffu), cax, cbx), 0.f) : bf2f((u) & 0xffffu))
        #define FY(u) (BN ? fmaxf(fmaf(bf2f((u) >> 16),    cay, cby), 0.f) : bf2f((u) >> 16))
        const unsigned int u0 = LD(node);
        float ax = FX(u0), ay = FY(u0);
        int e = beg;
        for (; e + 3 < end; e += 4) {
            const unsigned int ua = LD(col[e]);
            const unsigned int ub = LD(col[e + 1]);
            const unsigned int uc = LD(col[e + 2]);
            const unsigned int ud = LD(col[e + 3]);
            ax += FX(ua) + FX(ub) + FX(uc) + FX(ud);
            ay += FY(ua) + FY(ub) + FY(uc) + FY(ud);
        }
        for (; e < end; ++e) {
            const unsigned int u = LD(col[e]);
            ax += FX(u); ay += FY(u);
        }
        #undef LD
        #undef FX
        #undef FY
        *(unsigned int*)&out[node * 128 + lane * 2] = f2b(ax) | (f2b(ay) << 16);
    }
}

// ---------------------------------------------------------------- C = M @ W + bias (bf16 M/C, fp32 W/accum), fused BN stats
// NOTE: M may alias C only when FIN==128 (same row stride). Each block reads only its own
// 64 rows (LDS-staged, barriered) before the epilogue stores those rows.
struct GemmArgs {
    const ushort *mA, *mB;
    const float *W, *bias;
    ushort *cA, *cB;
    float *stA, *stB;
};

template<int FIN>
__global__ __launch_bounds__(256) void gemm16(GemmArgs g) {
    const int side = blockIdx.x >= NBG;
    const int bx = blockIdx.x - side * NBG;
    const ushort* __restrict__ M = side ? g.mB : g.mA;
    ushort* __restrict__ C = side ? g.cB : g.cA;
    float* __restrict__ stats = side ? g.stB : g.stA;

    __shared__ float xs[64][33];
    __shared__ float ws[32][128];
    const int t = threadIdx.x;
    const int r0 = bx * 64;
    const int ry = t >> 4, cx = t & 15, c0 = cx * 8;

    float acc[4][8];
    #pragma unroll
    for (int i = 0; i < 4; ++i)
        #pragma unroll
        for (int j = 0; j < 8; ++j) acc[i][j] = 0.f;

    for (int k0 = 0; k0 < FIN; k0 += 32) {
        {   // stage M tile (64 x 32 bf16 -> fp32)
            const int rr = t >> 2, kg = (t & 3) * 8;
            const int r = r0 + rr;
            uint4 v = make_uint4(0u, 0u, 0u, 0u);
            if (r < NN) v = *(const uint4*)&M[r * FIN + k0 + kg];
            xs[rr][kg + 0] = bf2f(v.x & 0xffffu); xs[rr][kg + 1] = bf2f(v.x >> 16);
            xs[rr][kg + 2] = bf2f(v.y & 0xffffu); xs[rr][kg + 3] = bf2f(v.y >> 16);
            xs[rr][kg + 4] = bf2f(v.z & 0xffffu); xs[rr][kg + 5] = bf2f(v.z >> 16);
            xs[rr][kg + 6] = bf2f(v.w & 0xffffu); xs[rr][kg + 7] = bf2f(v.w >> 16);
            // stage W tile (32 x 128 fp32)
            const int kk0 = t >> 5, cg = (t & 31) * 4;
            #pragma unroll
            for (int it = 0; it < 4; ++it) {
                const int kk = kk0 + it * 8;
                *(float4*)&ws[kk][cg] = *(const float4*)&g.W[(k0 + kk) * HID + cg];
            }
        }
        __syncthreads();
        #pragma unroll
        for (int k = 0; k < 32; ++k) {
            float xv[4], wv[8];
            #pragma unroll
            for (int i = 0; i < 4; ++i) xv[i] = xs[ry * 4 + i][k];
            *(float4*)&wv[0] = *(const float4*)&ws[k][c0];
            *(float4*)&wv[4] = *(const float4*)&ws[k][c0 + 4];
            #pragma unroll
            for (int i = 0; i < 4; ++i)
                #pragma unroll
                for (int j = 0; j < 8; ++j) acc[i][j] = fmaf(xv[i], wv[j], acc[i][j]);
        }
        __syncthreads();
    }
    // ---- epilogue: bias, bf16 store, per-block BN partial stats (fp32, pre-rounding)
    float bv[8];
    *(float4*)&bv[0] = *(const float4*)&g.bias[c0];
    *(float4*)&bv[4] = *(const float4*)&g.bias[c0 + 4];
    float sc[8], qc[8];
    #pragma unroll
    for (int j = 0; j < 8; ++j) { sc[j] = 0.f; qc[j] = 0.f; }
    #pragma unroll
    for (int i = 0; i < 4; ++i) {
        const int r = r0 + ry * 4 + i;
        if (r < NN) {
            float o[8];
            #pragma unroll
            for (int j = 0; j < 8; ++j) {
                o[j] = acc[i][j] + bv[j];
                sc[j] += o[j];
                qc[j] = fmaf(o[j], o[j], qc[j]);
            }
            uint4 pk;
            pk.x = f2b(o[0]) | (f2b(o[1]) << 16);
            pk.y = f2b(o[2]) | (f2b(o[3]) << 16);
            pk.z = f2b(o[4]) | (f2b(o[5]) << 16);
            pk.w = f2b(o[6]) | (f2b(o[7]) << 16);
            *(uint4*)&C[r * HID + c0] = pk;
        }
    }
    float* red = &ws[0][0];   // ws dead after final barrier; 2048 floats
    #pragma unroll
    for (int j = 0; j < 8; ++j) red[ry * 128 + c0 + j] = sc[j];
    __syncthreads();
    if (t < 128) {
        float a = 0.f;
        #pragma unroll
        for (int k = 0; k < 16; ++k) a += red[k * 128 + t];
        unsafeAtomicAdd(&stats[t], a);
    }
    __syncthreads();
    #pragma unroll
    for (int j = 0; j < 8; ++j) red[ry * 128 + c0 + j] = qc[j];
    __syncthreads();
    if (t < 128) {
        float a = 0.f;
        #pragma unroll
        for (int k = 0; k < 16; ++k) a += red[k * 128 + t];
        unsafeAtomicAdd(&stats[128 + t], a);
    }
}

// ---------------------------------------------------------------- pool, both sides, BN3+ReLU fused (coef from raw stats)
struct PoolArgs {
    const ushort *hA, *hB;
    const void *btA, *btB;
    const float *stA, *stB;
    const float *gamma, *beta;
    float *pooled, *cnt;
    const int* flag;
};

__global__ __launch_bounds__(128) void pool16(PoolArgs p) {
    const int side = blockIdx.x >= NBG;
    const int bx = blockIdx.x - side * NBG;
    const ushort* __restrict__ h = side ? p.hB : p.hA;
    const void* __restrict__ batch = side ? p.btB : p.btA;
    const float* __restrict__ st = side ? p.stB : p.stA;
    float* pooled = p.pooled + side * NG * HID;
    float* cnt = p.cnt + side * NG;
    const bool is64 = (*p.flag != 0);
    const int c = threadIdx.x;

    const float inv_n = 1.f / (float)NN;
    const float mu = st[c] * inv_n;
    const float var = st[128 + c] * inv_n - mu * mu;
    const float ca = p.gamma[c] * rsqrtf(var + BN_EPS);
    const float cb = fmaf(-mu, ca, p.beta[c]);

    const int rbeg = bx * 64;
    if (rbeg >= NN) return;
    const int rend = min(rbeg + 64, NN);
    const int g0 = load_idx(batch, rbeg, is64);
    const int g1 = load_idx(batch, rend - 1, is64);
    if (g0 == g1) {
        float acc = 0.f;
        #pragma unroll 8
        for (int r = rbeg; r < rend; ++r)
            acc += fmaxf(fmaf(bf2f(h[r * HID + c]), ca, cb), 0.f);
        unsafeAtomicAdd(&pooled[g0 * HID + c], acc);
        if (c == 0) unsafeAtomicAdd(&cnt[g0], (float)(rend - rbeg));
        return;
    }
    int gprev = g0;
    float acc = 0.f; int run = 0;
    for (int r = rbeg; r < rend; ++r) {
        const int g = load_idx(batch, r, is64);
        if (g != gprev) {
            unsafeAtomicAdd(&pooled[gprev * HID + c], acc);
            if (c == 0) unsafeAtomicAdd(&cnt[gprev], (float)run);
            acc = 0.f; run = 0; gprev = g;
        }
        acc += fmaxf(fmaf(bf2f(h[r * HID + c]), ca, cb), 0.f);
        ++run;
    }
    unsafeAtomicAdd(&pooled[gprev * HID + c], acc);
    if (c == 0) unsafeAtomicAdd(&cnt[gprev], (float)run);
}

__global__ __launch_bounds__(64) void pool_proj(const float* __restrict__ pooled,
                                                const float* __restrict__ cnt,
                                                const float* __restrict__ Wf,
                                                const float* __restrict__ bf,
                                                float* __restrict__ v) {
    const int side = blockIdx.x >= NG;
    const int g = blockIdx.x - side * NG;
    const int c = threadIdx.x;  // 64
    const float* pp = pooled + side * NG * HID + g * HID;
    const float inv = 1.f / fmaxf(cnt[side * NG + g], 1.f);
    float acc = 0.f;
    for (int k = 0; k < HID; ++k) acc = fmaf(pp[k], Wf[k * EMB + c], acc);
    v[side * NG * EMB + g * EMB + c] = fmaf(acc, inv, bf[c]);
}

// ---------------------------------------------------------------- classifier head
__global__ __launch_bounds__(256) void classifier(const float* __restrict__ v1,
                                                  const float* __restrict__ v2,
                                                  const float* __restrict__ Wc1,
                                                  const float* __restrict__ bc1,
                                                  const float* __restrict__ Wc2,
                                                  const float* __restrict__ bc2,
                                                  float* __restrict__ out) {
    const int g = threadIdx.x;
    if (g >= NG) return;
    float d[EMB];
    #pragma unroll
    for (int c = 0; c < EMB; ++c) d[c] = fabsf(v1[g * EMB + c] - v2[g * EMB + c]);
    float o = bc2[0];
    for (int j = 0; j < 32; ++j) {
        float h = bc1[j];
        #pragma unroll
        for (int c = 0; c < EMB; ++c) h = fmaf(d[c], Wc1[c * 32 + j], h);
        h = fmaxf(h, 0.f);
        o = fmaf(h, Wc2[j], o);
    }
    out[g] = 1.f / (1.f + expf(-o));
}

// ---------------------------------------------------------------- launch
extern "C" void kernel_launch(void* const* d_in, const int* in_sizes, int n_in,
                              void* d_out, int out_size, void* d_ws, size_t ws_size,
                              hipStream_t stream) {
    const float* x1 = (const float*)d_in[0];
    const float* x2 = (const float*)d_in[1];
    const void* ei1 = d_in[2];
    const void* ei2 = d_in[3];
    const void* bt1 = d_in[4];
    const void* bt2 = d_in[5];
    const float* W[3]  = {(const float*)d_in[6],  (const float*)d_in[10], (const float*)d_in[14]};
    const float* bb[3] = {(const float*)d_in[7],  (const float*)d_in[11], (const float*)d_in[15]};
    const float* gg[3] = {(const float*)d_in[8],  (const float*)d_in[12], (const float*)d_in[16]};
    const float* be[3] = {(const float*)d_in[9],  (const float*)d_in[13], (const float*)d_in[17]};
    const float* Wf  = (const float*)d_in[18];
    const float* bfv = (const float*)d_in[19];
    const float* Wc1 = (const float*)d_in[20];
    const float* bc1 = (const float*)d_in[21];
    const float* Wc2 = (const float*)d_in[22];
    const float* bc2 = (const float*)d_in[23];

    // ---- workspace carve-up (256B-aligned)
    char* cur = (char*)d_ws;
    auto alloc = [&](size_t bytes) -> void* {
        void* p = cur;
        cur += (bytes + 255) & ~(size_t)255;
        return p;
    };
    ushort* P0 = (ushort*)alloc((size_t)NN * HID * 2);   // side0: X16 / h1 / agg3 / h3
    ushort* P1 = (ushort*)alloc((size_t)NN * HID * 2);
    ushort* Q0 = (ushort*)alloc((size_t)NN * HID * 2);   // side0: agg1 / agg2 / h2
    ushort* Q1 = (ushort*)alloc((size_t)NN * HID * 2);
    int* deg2   = (int*)alloc((size_t)2 * NN * 4);       // degA | degB (one memset)
    int* rpA    = (int*)alloc((size_t)(NN + 1) * 4);
    int* rpB    = (int*)alloc((size_t)(NN + 1) * 4);
    int* curA   = (int*)alloc((size_t)NN * 4);
    int* curB   = (int*)alloc((size_t)NN * 4);
    int* bsum   = (int*)alloc(256 * 4);
    int* boff   = (int*)alloc(256 * 4);
    int* colA   = (int*)alloc((size_t)NE * 4);
    int* colB   = (int*)alloc((size_t)NE * 4);
    int* flag   = (int*)alloc(64);
    float* zreg = (float*)alloc((size_t)(6 * 256 + 2 * NG * HID + 2 * NG) * 4);  // stats|pooled|cnt
    float* stats  = zreg;                         // 6 x 256 (sum[128], sumsq[128])
    float* pooled = stats + 6 * 256;              // 2 x G x 128
    float* cnt    = pooled + 2 * NG * HID;        // 2 x G
    float* vv     = (float*)alloc((size_t)2 * NG * EMB * 4);
    int* degA = deg2, *degB = deg2 + NN;

    hipMemsetAsync(deg2, 0, (size_t)2 * NN * 4, stream);
    hipMemsetAsync(zreg, 0, (size_t)(6 * 256 + 2 * NG * HID + 2 * NG) * 4, stream);
    detect_i64_kernel<<<1, 64, 0, stream>>>(ei1, flag);
    convert_x<<<(2 * NN * 16) / 256, 256, 0, stream>>>(x1, x2, P0, P1);

    // ---- CSR build (both sides fused)
    const int EB2 = (2 * NE + 255) / 256;
    csr_hist2<<<EB2, 256, 0, stream>>>(ei1, ei2, degA, degB, flag);
    scan_block_sums2<<<2 * SNB, 256, 0, stream>>>(degA, degB, bsum);
    scan_bsums2<<<2, 128, 0, stream>>>(bsum, boff, rpA, rpB);
    scan_fill2<<<2 * SNB, 256, 0, stream>>>(degA, degB, boff, rpA, rpB, curA, curB);
    csr_fill2<<<EB2, 256, 0, stream>>>(ei1, ei2, curA, curB, colA, colB, flag);

    float* st0A = stats + 0 * 256, *st0B = stats + 1 * 256;
    float* st1A = stats + 2 * 256, *st1B = stats + 3 * 256;
    float* st2A = stats + 4 * 256, *st2B = stats + 5 * 256;

    // ---- layer 1: agg1 = agg(X16) P->Q ; h1 = gemm64(Q) -> P (X16 dead)
    {
        GatherArgs a = {P0, P1, rpA, rpB, colA, colB, nullptr, nullptr, nullptr, nullptr, Q0, Q1};
        gather16<64, false><<<2 * GBLK, 256, 0, stream>>>(a);
        GemmArgs g = {Q0, Q1, W[0], bb[0], P0, P1, st0A, st0B};
        gemm16<64><<<2 * NBG, 256, 0, stream>>>(g);
    }
    // ---- layer 2: agg2 = agg(f1(h1)) P->Q ; h2 = gemm128(Q) -> Q (in-place)
    {
        GatherArgs a = {P0, P1, rpA, rpB, colA, colB, st0A, st0B, gg[0], be[0], Q0, Q1};
        gather16<128, true><<<2 * GBLK, 256, 0, stream>>>(a);
        GemmArgs g = {Q0, Q1, W[1], bb[1], Q0, Q1, st1A, st1B};
        gemm16<128><<<2 * NBG, 256, 0, stream>>>(g);
    }
    // ---- layer 3: agg3 = agg(f2(h2)) Q->P (h1 dead) ; h3 = gemm128(P) -> P (in-place)
    {
        GatherArgs a = {Q0, Q1, rpA, rpB, colA, colB, st1A, st1B, gg[1], be[1], P0, P1};
        gather16<128, true><<<2 * GBLK, 256, 0, stream>>>(a);
        GemmArgs g = {P0, P1, W[2], bb[2], P0, P1, st2A, st2B};
        gemm16<128><<<2 * NBG, 256, 0, stream>>>(g);
    }
    // ---- pool (BN3+ReLU fused), projection, classifier
    {
        PoolArgs p = {P0, P1, bt1, bt2, st2A, st2B, gg[2], be[2], pooled, cnt, flag};
        pool16<<<2 * NBG, 128, 0, stream>>>(p);
    }
    pool_proj<<<2 * NG, 64, 0, stream>>>(pooled, cnt, Wf, bfv, vv);
    classifier<<<1, 256, 0, stream>>>(vv, vv + NG * EMB, Wc1, bc1, Wc2, bc2, (float*)d_out);
}

// Round 7
// 992.329 us; speedup vs baseline: 5.9086x; 1.2082x over previous
//
#include <hip/hip_runtime.h>
#include <hip/hip_bf16.h>
#include <math.h>

#define NN 100000
#define NE 1280000
#define NG 256
#define HID 128
#define EMB 64
#define BN_EPS 1e-5f
#define SB 1024
#define SNB ((NN + SB - 1) / SB)   // 98
#define GBLK 25000                 // gather blocks per side (4 nodes/block)
#define NBG 1563                   // gemm/pool blocks per side (64 rows/block)
#define PART ((NN + 7) / 8)        // 12500 dsts per XCD partition
#define FCH 2048                   // edges per fill chunk
#define NCH (NE / FCH)             // 625

typedef __attribute__((ext_vector_type(8))) __bf16 bf16x8;
typedef __attribute__((ext_vector_type(4))) float f32x4;

// ---------------------------------------------------------------- bf16 helpers (manual, RNE)
__device__ __forceinline__ float bf2f(unsigned int u) { return __uint_as_float(u << 16); }
__device__ __forceinline__ unsigned int f2b(float f) {
    unsigned int u = __float_as_uint(f);
    return (u + 0x7fffu + ((u >> 16) & 1u)) >> 16;
}

// ---------------------------------------------------------------- utilities
__global__ void detect_i64_kernel(const void* __restrict__ ei, int* __restrict__ flag) {
    if (threadIdx.x == 0 && blockIdx.x == 0) {
        const unsigned long long* p = (const unsigned long long*)ei;
        int is64 = 1;
        #pragma unroll
        for (int i = 0; i < 16; ++i)
            if (p[i] >= (1ull << 32)) is64 = 0;
        *flag = is64;
    }
}

__device__ __forceinline__ int load_idx(const void* p, int i, bool is64) {
    return is64 ? (int)((const long long*)p)[i] : ((const int*)p)[i];
}

// ---------------------------------------------------------------- x -> bf16 (both sides)
__global__ __launch_bounds__(256) void convert_x(const float* __restrict__ x1,
                                                 const float* __restrict__ x2,
                                                 ushort* __restrict__ o1,
                                                 ushort* __restrict__ o2) {
    const int per = NN * 16;
    const int i = blockIdx.x * 256 + threadIdx.x;
    const int side = i >= per;
    const int j = i - side * per;
    const float4 v = ((const float4*)(side ? x2 : x1))[j];
    ushort4 o;
    o.x = (ushort)f2b(v.x); o.y = (ushort)f2b(v.y);
    o.z = (ushort)f2b(v.z); o.w = (ushort)f2b(v.w);
    ((ushort4*)(side ? o2 : o1))[j] = o;
}

// ---------------------------------------------------------------- weights -> bf16 transposed WT[c][k]
__global__ __launch_bounds__(256) void prep_weights(const float* __restrict__ W1,
                                                    const float* __restrict__ W2,
                                                    const float* __restrict__ W3,
                                                    ushort* __restrict__ T1,
                                                    ushort* __restrict__ T2,
                                                    ushort* __restrict__ T3) {
    const int i = blockIdx.x * 256 + threadIdx.x;   // 40960 total
    if (i < 8192) {                 // W1: [64][128]
        const int k = i >> 7, c = i & 127;
        T1[c * 64 + k] = (ushort)f2b(W1[i]);
    } else if (i < 24576) {         // W2: [128][128]
        const int j = i - 8192, k = j >> 7, c = j & 127;
        T2[c * 128 + k] = (ushort)f2b(W2[j]);
    } else if (i < 40960) {         // W3
        const int j = i - 24576, k = j >> 7, c = j & 127;
        T3[c * 128 + k] = (ushort)f2b(W3[j]);
    }
}

// ---------------------------------------------------------------- CSR build
__global__ __launch_bounds__(256) void csr_hist2(const void* __restrict__ e1,
                                                 const void* __restrict__ e2,
                                                 int* __restrict__ degA,
                                                 int* __restrict__ degB,
                                                 const int* __restrict__ flag) {
    const bool is64 = (*flag != 0);
    const int i = blockIdx.x * 256 + threadIdx.x;
    if (i < 2 * NE) {
        const int side = i >= NE;
        const int j = i - side * NE;
        atomicAdd(&(side ? degB : degA)[load_idx(side ? e2 : e1, NE + j, is64)], 1);
    }
}

__global__ __launch_bounds__(256) void scan_block_sums2(const int* __restrict__ degA,
                                                        const int* __restrict__ degB,
                                                        int* __restrict__ bsum) {
    const int side = blockIdx.x >= SNB;
    const int bx = blockIdx.x - side * SNB;
    const int* deg = side ? degB : degA;
    const int t = threadIdx.x;
    const int base = bx * SB + t * 4;
    int s = 0;
    #pragma unroll
    for (int k = 0; k < 4; ++k) {
        const int i = base + k;
        if (i < NN) s += deg[i];
    }
    __shared__ int red[256];
    red[t] = s;
    __syncthreads();
    for (int off = 128; off > 0; off >>= 1) {
        if (t < off) red[t] += red[t + off];
        __syncthreads();
    }
    if (t == 0) bsum[side * 128 + bx] = red[0];
}

__global__ __launch_bounds__(128) void scan_bsums2(const int* __restrict__ bsum,
                                                   int* __restrict__ boff,
                                                   int* __restrict__ rpA,
                                                   int* __restrict__ rpB) {
    const int side = blockIdx.x;
    __shared__ int s[128];
    const int t = threadIdx.x;
    s[t] = (t < SNB) ? bsum[side * 128 + t] : 0;
    __syncthreads();
    for (int off = 1; off < 128; off <<= 1) {
        const int v = (t >= off) ? s[t - off] : 0;
        __syncthreads();
        s[t] += v;
        __syncthreads();
    }
    boff[side * 128 + t] = (t == 0) ? 0 : s[t - 1];
    if (t == 0) (side ? rpB : rpA)[NN] = s[SNB - 1];
}

__global__ __launch_bounds__(256) void scan_fill2(const int* __restrict__ degA,
                                                  const int* __restrict__ degB,
                                                  const int* __restrict__ boff,
                                                  int* __restrict__ rpA,
                                                  int* __restrict__ rpB,
                                                  int* __restrict__ curA,
                                                  int* __restrict__ curB) {
    const int side = blockIdx.x >= SNB;
    const int bx = blockIdx.x - side * SNB;
    const int* deg = side ? degB : degA;
    int* rowptr = side ? rpB : rpA;
    int* cursor = side ? curB : curA;
    const int t = threadIdx.x;
    const int base = bx * SB + t * 4;
    int v[4], s = 0;
    #pragma unroll
    for (int k = 0; k < 4; ++k) {
        const int i = base + k;
        v[k] = (i < NN) ? deg[i] : 0;
        s += v[k];
    }
    __shared__ int red[256];
    red[t] = s;
    __syncthreads();
    for (int off = 1; off < 256; off <<= 1) {
        const int x = (t >= off) ? red[t - off] : 0;
        __syncthreads();
        red[t] += x;
        __syncthreads();
    }
    int run = boff[side * 128 + bx] + ((t == 0) ? 0 : red[t - 1]);
    #pragma unroll
    for (int k = 0; k < 4; ++k) {
        const int i = base + k;
        if (i < NN) {
            rowptr[i] = run;
            cursor[i] = run;
            run += v[k];
        }
    }
}

// fill, dst-partitioned so each col region is written by one XCD (bid%8 ~ XCD round-robin).
// grid = 8 * NCH * 2; block bid: partition g=bid&7, q=bid>>3 -> side/chunk.
__global__ __launch_bounds__(256) void csr_fill_part(const void* __restrict__ e1,
                                                     const void* __restrict__ e2,
                                                     int* __restrict__ curA,
                                                     int* __restrict__ curB,
                                                     int* __restrict__ colA,
                                                     int* __restrict__ colB,
                                                     const int* __restrict__ flag) {
    const bool is64 = (*flag != 0);
    const int g = blockIdx.x & 7;
    const int q = blockIdx.x >> 3;          // 0 .. 2*NCH-1
    const int side = q >= NCH;
    const int chunk = q - side * NCH;
    const void* __restrict__ e = side ? e2 : e1;
    int* __restrict__ cur = side ? curB : curA;
    int* __restrict__ col = side ? colB : colA;
    const int lo = g * PART;
    const int hi = min(lo + PART, NN);
    const int base = chunk * FCH;
    for (int i = base + threadIdx.x; i < base + FCH; i += 256) {
        const int d = load_idx(e, NE + i, is64);
        if (d >= lo && d < hi) {
            const int pos = atomicAdd(&cur[d], 1);
            col[pos] = load_idx(e, i, is64);
        }
    }
}

// ---------------------------------------------------------------- gather (bf16 in/out, fp32 accum)
struct GatherArgs {
    const ushort *xA, *xB;
    const int *rpA, *rpB, *colA, *colB;
    const float *stA, *stB;        // raw (sum[128], sumsq[128]) or null
    const float *gamma, *beta;
    ushort *oA, *oB;
};

template<int F, bool BN>
__global__ __launch_bounds__(256) void gather16(GatherArgs a) {
    const int side = blockIdx.x >= GBLK;
    const int bx = blockIdx.x - side * GBLK;
    const ushort* __restrict__ x = side ? a.xB : a.xA;
    const int* __restrict__ rowptr = side ? a.rpB : a.rpA;
    const int* __restrict__ col = side ? a.colB : a.colA;
    ushort* __restrict__ out = side ? a.oB : a.oA;

    const int node = (bx * 256 + threadIdx.x) >> 6;
    const int lane = threadIdx.x & 63;
    if (node >= NN) return;
    const int beg = rowptr[node], end = rowptr[node + 1];

    if (F == 64) {
        float acc = bf2f(x[node * 64 + lane]);
        int e = beg;
        for (; e + 3 < end; e += 4) {
            const int s0 = col[e], s1 = col[e + 1], s2 = col[e + 2], s3 = col[e + 3];
            acc += bf2f(x[s0 * 64 + lane]) + bf2f(x[s1 * 64 + lane])
                 + bf2f(x[s2 * 64 + lane]) + bf2f(x[s3 * 64 + lane]);
        }
        for (; e < end; ++e) acc += bf2f(x[col[e] * 64 + lane]);
        out[node * 64 + lane] = (ushort)f2b(acc);
    } else {
        float cax = 1.f, cay = 1.f, cbx = 0.f, cby = 0.f;
        if (BN) {
            const float* st = side ? a.stB : a.stA;
            const int c0 = lane * 2, c1 = c0 + 1;
            const float inv_n = 1.f / (float)NN;
            const float mu0 = st[c0] * inv_n, mu1 = st[c1] * inv_n;
            const float v0 = st[128 + c0] * inv_n - mu0 * mu0;
            const float v1 = st[128 + c1] * inv_n - mu1 * mu1;
            cax = a.gamma[c0] * rsqrtf(v0 + BN_EPS);
            cay = a.gamma[c1] * rsqrtf(v1 + BN_EPS);
            cbx = fmaf(-mu0, cax, a.beta[c0]);
            cby = fmaf(-mu1, cay, a.beta[c1]);
        }
        #define LD(s) (*(const unsigned int*)&x[(s) * 128 + lane * 2])
        #define FX(u) (BN ? fmaxf(fmaf(bf2f((u) & 0xffffu), cax, cbx), 0.f) : bf2f((u) & 0xffffu))
        #define FY(u) (BN ? fmaxf(fmaf(bf2f((u) >> 16),    cay, cby), 0.f) : bf2f((u) >> 16))
        const unsigned int u0 = LD(node);
        float ax = FX(u0), ay = FY(u0);
        int e = beg;
        for (; e + 3 < end; e += 4) {
            const unsigned int ua = LD(col[e]);
            const unsigned int ub = LD(col[e + 1]);
            const unsigned int uc = LD(col[e + 2]);
            const unsigned int ud = LD(col[e + 3]);
            ax += FX(ua) + FX(ub) + FX(uc) + FX(ud);
            ay += FY(ua) + FY(ub) + FY(uc) + FY(ud);
        }
        for (; e < end; ++e) {
            const unsigned int u = LD(col[e]);
            ax += FX(u); ay += FY(u);
        }
        #undef LD
        #undef FX
        #undef FY
        *(unsigned int*)&out[node * 128 + lane * 2] = f2b(ax) | (f2b(ay) << 16);
    }
}

// ---------------------------------------------------------------- MFMA GEMM: C = M @ W + bias (bf16), fused BN stats
// 64 rows x 128 cols per block; 4 waves, each owns a 32-col slice (4x2 frags of 16x16, K=32 chunks).
// M may alias C: all global M reads complete (LDS-staged, barriered) before epilogue stores.
struct GemmArgs {
    const ushort *mA, *mB;
    const ushort *WT;              // [128][FIN] bf16, transposed
    const float *bias;
    ushort *cA, *cB;
    float *stA, *stB;
};

template<int FIN>
__global__ __launch_bounds__(256) void gemm_mfma(GemmArgs g) {
    constexpr int FP = FIN + 8;          // padded LDS stride (bf16 units)
    constexpr int CPR = FIN / 8;         // 16B chunks per row
    const int side = blockIdx.x >= NBG;
    const int bx = blockIdx.x - side * NBG;
    const ushort* __restrict__ M = side ? g.mB : g.mA;
    ushort* __restrict__ C = side ? g.cB : g.cA;
    float* __restrict__ stats = side ? g.stB : g.stA;

    __shared__ ushort sh[64 * 136 + 128 * FP];
    ushort* Ml = sh;                     // M tile (stride FP); later C tile (stride 136)
    ushort* Wl = sh + 64 * 136;          // WT tile (stride FP); later stats red (fp32)

    const int t = threadIdx.x;
    const int w = t >> 6;                // wave 0..3
    const int l = t & 63;
    const int lr = l & 15;
    const int lg = l >> 4;
    const int r0 = bx * 64;

    // ---- stage M (64 x FIN)
    #pragma unroll
    for (int it = 0; it < (64 * CPR) / 256; ++it) {
        const int cid = it * 256 + t;
        const int row = cid / CPR, cc = (cid % CPR) * 8;
        const int r = r0 + row;
        uint4 v = make_uint4(0u, 0u, 0u, 0u);
        if (r < NN) v = *(const uint4*)&M[(size_t)r * FIN + cc];
        *(uint4*)&Ml[row * FP + cc] = v;
    }
    // ---- stage WT (128 x FIN)
    #pragma unroll
    for (int it = 0; it < (128 * CPR) / 256; ++it) {
        const int cid = it * 256 + t;
        const int c = cid / CPR, kk = (cid % CPR) * 8;
        *(uint4*)&Wl[c * FP + kk] = *(const uint4*)&g.WT[c * FIN + kk];
    }
    __syncthreads();

    f32x4 acc[4][2];
    #pragma unroll
    for (int fi = 0; fi < 4; ++fi)
        #pragma unroll
        for (int fj = 0; fj < 2; ++fj)
            acc[fi][fj] = (f32x4){0.f, 0.f, 0.f, 0.f};

    #pragma unroll
    for (int kc = 0; kc < FIN / 32; ++kc) {
        const int kb = kc * 32 + lg * 8;
        bf16x8 a[4], b[2];
        #pragma unroll
        for (int fi = 0; fi < 4; ++fi)
            a[fi] = *(const bf16x8*)&Ml[(fi * 16 + lr) * FP + kb];
        #pragma unroll
        for (int fj = 0; fj < 2; ++fj)
            b[fj] = *(const bf16x8*)&Wl[(w * 32 + fj * 16 + lr) * FP + kb];
        #pragma unroll
        for (int fi = 0; fi < 4; ++fi)
            #pragma unroll
            for (int fj = 0; fj < 2; ++fj)
                acc[fi][fj] = __builtin_amdgcn_mfma_f32_16x16x32_bf16(a[fi], b[fj], acc[fi][fj], 0, 0, 0);
    }
    __syncthreads();   // all LDS reads done; Ml/Wl reusable

    // ---- bias add + stage C tile (bf16) into Ml (stride 136)
    #pragma unroll
    for (int fj = 0; fj < 2; ++fj) {
        const float bv = g.bias[w * 32 + fj * 16 + lr];
        #pragma unroll
        for (int fi = 0; fi < 4; ++fi)
            #pragma unroll
            for (int j = 0; j < 4; ++j)
                acc[fi][fj][j] += bv;
    }
    #pragma unroll
    for (int fi = 0; fi < 4; ++fi)
        #pragma unroll
        for (int fj = 0; fj < 2; ++fj)
            #pragma unroll
            for (int j = 0; j < 4; ++j) {
                const int row = fi * 16 + lg * 4 + j;
                const int c = w * 32 + fj * 16 + lr;
                Ml[row * 136 + c] = (ushort)f2b(acc[fi][fj][j]);
            }
    __syncthreads();

    // ---- epilogue: coalesced global store + BN partial stats (from rounded values)
    const int ry = t >> 4, c0 = (t & 15) * 8;
    float sc[8], qc[8];
    #pragma unroll
    for (int j = 0; j < 8; ++j) { sc[j] = 0.f; qc[j] = 0.f; }
    #pragma unroll
    for (int i = 0; i < 4; ++i) {
        const int rr = ry * 4 + i;
        const int r = r0 + rr;
        if (r < NN) {
            const uint4 pk = *(const uint4*)&Ml[rr * 136 + c0];
            const unsigned int uu[4] = {pk.x, pk.y, pk.z, pk.w};
            #pragma unroll
            for (int q = 0; q < 4; ++q) {
                const float e0 = bf2f(uu[q] & 0xffffu);
                const float e1 = bf2f(uu[q] >> 16);
                sc[2 * q] += e0;       sc[2 * q + 1] += e1;
                qc[2 * q] = fmaf(e0, e0, qc[2 * q]);
                qc[2 * q + 1] = fmaf(e1, e1, qc[2 * q + 1]);
            }
            *(uint4*)&C[(size_t)r * HID + c0] = pk;
        }
    }
    float* red = (float*)Wl;             // 2048 floats
    #pragma unroll
    for (int j = 0; j < 8; ++j) red[ry * 128 + c0 + j] = sc[j];
    __syncthreads();
    if (t < 128) {
        float a = 0.f;
        #pragma unroll
        for (int k = 0; k < 16; ++k) a += red[k * 128 + t];
        unsafeAtomicAdd(&stats[t], a);
    }
    __syncthreads();
    #pragma unroll
    for (int j = 0; j < 8; ++j) red[ry * 128 + c0 + j] = qc[j];
    __syncthreads();
    if (t < 128) {
        float a = 0.f;
        #pragma unroll
        for (int k = 0; k < 16; ++k) a += red[k * 128 + t];
        unsafeAtomicAdd(&stats[128 + t], a);
    }
}

// ---------------------------------------------------------------- pool, both sides, BN3+ReLU fused
struct PoolArgs {
    const ushort *hA, *hB;
    const void *btA, *btB;
    const float *stA, *stB;
    const float *gamma, *beta;
    float *pooled, *cnt;
    const int* flag;
};

__global__ __launch_bounds__(128) void pool16(PoolArgs p) {
    const int side = blockIdx.x >= NBG;
    const int bx = blockIdx.x - side * NBG;
    const ushort* __restrict__ h = side ? p.hB : p.hA;
    const void* __restrict__ batch = side ? p.btB : p.btA;
    const float* __restrict__ st = side ? p.stB : p.stA;
    float* pooled = p.pooled + side * NG * HID;
    float* cnt = p.cnt + side * NG;
    const bool is64 = (*p.flag != 0);
    const int c = threadIdx.x;

    const float inv_n = 1.f / (float)NN;
    const float mu = st[c] * inv_n;
    const float var = st[128 + c] * inv_n - mu * mu;
    const float ca = p.gamma[c] * rsqrtf(var + BN_EPS);
    const float cb = fmaf(-mu, ca, p.beta[c]);

    const int rbeg = bx * 64;
    if (rbeg >= NN) return;
    const int rend = min(rbeg + 64, NN);
    const int g0 = load_idx(batch, rbeg, is64);
    const int g1 = load_idx(batch, rend - 1, is64);
    if (g0 == g1) {
        float acc = 0.f;
        #pragma unroll 8
        for (int r = rbeg; r < rend; ++r)
            acc += fmaxf(fmaf(bf2f(h[r * HID + c]), ca, cb), 0.f);
        unsafeAtomicAdd(&pooled[g0 * HID + c], acc);
        if (c == 0) unsafeAtomicAdd(&cnt[g0], (float)(rend - rbeg));
        return;
    }
    int gprev = g0;
    float acc = 0.f; int run = 0;
    for (int r = rbeg; r < rend; ++r) {
        const int g = load_idx(batch, r, is64);
        if (g != gprev) {
            unsafeAtomicAdd(&pooled[gprev * HID + c], acc);
            if (c == 0) unsafeAtomicAdd(&cnt[gprev], (float)run);
            acc = 0.f; run = 0; gprev = g;
        }
        acc += fmaxf(fmaf(bf2f(h[r * HID + c]), ca, cb), 0.f);
        ++run;
    }
    unsafeAtomicAdd(&pooled[gprev * HID + c], acc);
    if (c == 0) unsafeAtomicAdd(&cnt[gprev], (float)run);
}

__global__ __launch_bounds__(64) void pool_proj(const float* __restrict__ pooled,
                                                const float* __restrict__ cnt,
                                                const float* __restrict__ Wf,
                                                const float* __restrict__ bf,
                                                float* __restrict__ v) {
    const int side = blockIdx.x >= NG;
    const int g = blockIdx.x - side * NG;
    const int c = threadIdx.x;  // 64
    const float* pp = pooled + side * NG * HID + g * HID;
    const float inv = 1.f / fmaxf(cnt[side * NG + g], 1.f);
    float acc = 0.f;
    for (int k = 0; k < HID; ++k) acc = fmaf(pp[k], Wf[k * EMB + c], acc);
    v[side * NG * EMB + g * EMB + c] = fmaf(acc, inv, bf[c]);
}

// ---------------------------------------------------------------- classifier head
__global__ __launch_bounds__(256) void classifier(const float* __restrict__ v1,
                                                  const float* __restrict__ v2,
                                                  const float* __restrict__ Wc1,
                                                  const float* __restrict__ bc1,
                                                  const float* __restrict__ Wc2,
                                                  const float* __restrict__ bc2,
                                                  float* __restrict__ out) {
    const int g = threadIdx.x;
    if (g >= NG) return;
    float d[EMB];
    #pragma unroll
    for (int c = 0; c < EMB; ++c) d[c] = fabsf(v1[g * EMB + c] - v2[g * EMB + c]);
    float o = bc2[0];
    for (int j = 0; j < 32; ++j) {
        float h = bc1[j];
        #pragma unroll
        for (int c = 0; c < EMB; ++c) h = fmaf(d[c], Wc1[c * 32 + j], h);
        h = fmaxf(h, 0.f);
        o = fmaf(h, Wc2[j], o);
    }
    out[g] = 1.f / (1.f + expf(-o));
}

// ---------------------------------------------------------------- launch
extern "C" void kernel_launch(void* const* d_in, const int* in_sizes, int n_in,
                              void* d_out, int out_size, void* d_ws, size_t ws_size,
                              hipStream_t stream) {
    const float* x1 = (const float*)d_in[0];
    const float* x2 = (const float*)d_in[1];
    const void* ei1 = d_in[2];
    const void* ei2 = d_in[3];
    const void* bt1 = d_in[4];
    const void* bt2 = d_in[5];
    const float* W[3]  = {(const float*)d_in[6],  (const float*)d_in[10], (const float*)d_in[14]};
    const float* bb[3] = {(const float*)d_in[7],  (const float*)d_in[11], (const float*)d_in[15]};
    const float* gg[3] = {(const float*)d_in[8],  (const float*)d_in[12], (const float*)d_in[16]};
    const float* be[3] = {(const float*)d_in[9],  (const float*)d_in[13], (const float*)d_in[17]};
    const float* Wf  = (const float*)d_in[18];
    const float* bfv = (const float*)d_in[19];
    const float* Wc1 = (const float*)d_in[20];
    const float* bc1 = (const float*)d_in[21];
    const float* Wc2 = (const float*)d_in[22];
    const float* bc2 = (const float*)d_in[23];

    // ---- workspace carve-up (256B-aligned)
    char* cur = (char*)d_ws;
    auto alloc = [&](size_t bytes) -> void* {
        void* p = cur;
        cur += (bytes + 255) & ~(size_t)255;
        return p;
    };
    ushort* P0 = (ushort*)alloc((size_t)NN * HID * 2);   // side0: X16 / h1 / agg3 / h3
    ushort* P1 = (ushort*)alloc((size_t)NN * HID * 2);
    ushort* Q0 = (ushort*)alloc((size_t)NN * HID * 2);   // side0: agg1 / agg2 / h2
    ushort* Q1 = (ushort*)alloc((size_t)NN * HID * 2);
    int* deg2   = (int*)alloc((size_t)2 * NN * 4);
    int* rpA    = (int*)alloc((size_t)(NN + 1) * 4);
    int* rpB    = (int*)alloc((size_t)(NN + 1) * 4);
    int* curA   = (int*)alloc((size_t)NN * 4);
    int* curB   = (int*)alloc((size_t)NN * 4);
    int* bsum   = (int*)alloc(256 * 4);
    int* boff   = (int*)alloc(256 * 4);
    int* colA   = (int*)alloc((size_t)NE * 4);
    int* colB   = (int*)alloc((size_t)NE * 4);
    int* flag   = (int*)alloc(64);
    ushort* WT1 = (ushort*)alloc(128 * 64 * 2);
    ushort* WT2 = (ushort*)alloc(128 * 128 * 2);
    ushort* WT3 = (ushort*)alloc(128 * 128 * 2);
    float* zreg = (float*)alloc((size_t)(6 * 256 + 2 * NG * HID + 2 * NG) * 4);
    float* stats  = zreg;                         // 6 x 256 (sum[128], sumsq[128])
    float* pooled = stats + 6 * 256;              // 2 x G x 128
    float* cnt    = pooled + 2 * NG * HID;        // 2 x G
    float* vv     = (float*)alloc((size_t)2 * NG * EMB * 4);
    int* degA = deg2, *degB = deg2 + NN;

    hipMemsetAsync(deg2, 0, (size_t)2 * NN * 4, stream);
    hipMemsetAsync(zreg, 0, (size_t)(6 * 256 + 2 * NG * HID + 2 * NG) * 4, stream);
    detect_i64_kernel<<<1, 64, 0, stream>>>(ei1, flag);
    convert_x<<<(2 * NN * 16) / 256, 256, 0, stream>>>(x1, x2, P0, P1);
    prep_weights<<<160, 256, 0, stream>>>(W[0], W[1], W[2], WT1, WT2, WT3);

    // ---- CSR build (both sides fused; partitioned fill)
    const int EB2 = (2 * NE + 255) / 256;
    csr_hist2<<<EB2, 256, 0, stream>>>(ei1, ei2, degA, degB, flag);
    scan_block_sums2<<<2 * SNB, 256, 0, stream>>>(degA, degB, bsum);
    scan_bsums2<<<2, 128, 0, stream>>>(bsum, boff, rpA, rpB);
    scan_fill2<<<2 * SNB, 256, 0, stream>>>(degA, degB, boff, rpA, rpB, curA, curB);
    csr_fill_part<<<8 * 2 * NCH, 256, 0, stream>>>(ei1, ei2, curA, curB, colA, colB, flag);

    float* st0A = stats + 0 * 256, *st0B = stats + 1 * 256;
    float* st1A = stats + 2 * 256, *st1B = stats + 3 * 256;
    float* st2A = stats + 4 * 256, *st2B = stats + 5 * 256;

    // ---- layer 1: agg1 = agg(X16) P->Q ; h1 = gemm64(Q) -> P
    {
        GatherArgs a = {P0, P1, rpA, rpB, colA, colB, nullptr, nullptr, nullptr, nullptr, Q0, Q1};
        gather16<64, false><<<2 * GBLK, 256, 0, stream>>>(a);
        GemmArgs g = {Q0, Q1, WT1, bb[0], P0, P1, st0A, st0B};
        gemm_mfma<64><<<2 * NBG, 256, 0, stream>>>(g);
    }
    // ---- layer 2: agg2 = agg(f1(h1)) P->Q ; h2 = gemm128(Q) -> Q (in-place)
    {
        GatherArgs a = {P0, P1, rpA, rpB, colA, colB, st0A, st0B, gg[0], be[0], Q0, Q1};
        gather16<128, true><<<2 * GBLK, 256, 0, stream>>>(a);
        GemmArgs g = {Q0, Q1, WT2, bb[1], Q0, Q1, st1A, st1B};
        gemm_mfma<128><<<2 * NBG, 256, 0, stream>>>(g);
    }
    // ---- layer 3: agg3 = agg(f2(h2)) Q->P ; h3 = gemm128(P) -> P (in-place)
    {
        GatherArgs a = {Q0, Q1, rpA, rpB, colA, colB, st1A, st1B, gg[1], be[1], P0, P1};
        gather16<128, true><<<2 * GBLK, 256, 0, stream>>>(a);
        GemmArgs g = {P0, P1, WT3, bb[2], P0, P1, st2A, st2B};
        gemm_mfma<128><<<2 * NBG, 256, 0, stream>>>(g);
    }
    // ---- pool (BN3+ReLU fused), projection, classifier
    {
        PoolArgs p = {P0, P1, bt1, bt2, st2A, st2B, gg[2], be[2], pooled, cnt, flag};
        pool16<<<2 * NBG, 128, 0, stream>>>(p);
    }
    pool_proj<<<2 * NG, 64, 0, stream>>>(pooled, cnt, Wf, bfv, vv);
    classifier<<<1, 256, 0, stream>>>(vv, vv + NG * EMB, Wc1, bc1, Wc2, bc2, (float*)d_out);
}

// Round 8
// 930.996 us; speedup vs baseline: 6.2979x; 1.0659x over previous
//
#include <hip/hip_runtime.h>
#include <hip/hip_bf16.h>
#include <math.h>

#define NN 100000
#define NE 1280000
#define NG 256
#define HID 128
#define EMB 64
#define BN_EPS 1e-5f
#define SB 1024
#define SNB ((NN + SB - 1) / SB)   // 98
#define NBG 1563                   // gemm/pool blocks per side (64 rows/block)
#define NB4 25000                  // gather64 blocks per side (4 nodes/block)
#define PART ((NN + 7) / 8)        // 12500 dsts per XCD partition
#define FCH 2048                   // edges per fill chunk
#define NCH (NE / FCH)             // 625

typedef __attribute__((ext_vector_type(8))) __bf16 bf16x8;
typedef __attribute__((ext_vector_type(4))) float f32x4;

// ---------------------------------------------------------------- bf16 helpers (manual, RNE)
__device__ __forceinline__ float bf2f(unsigned int u) { return __uint_as_float(u << 16); }
__device__ __forceinline__ unsigned int f2b(float f) {
    unsigned int u = __float_as_uint(f);
    return (u + 0x7fffu + ((u >> 16) & 1u)) >> 16;
}

// ---------------------------------------------------------------- utilities
__global__ void detect_i64_kernel(const void* __restrict__ ei, int* __restrict__ flag) {
    if (threadIdx.x == 0 && blockIdx.x == 0) {
        const unsigned long long* p = (const unsigned long long*)ei;
        int is64 = 1;
        #pragma unroll
        for (int i = 0; i < 16; ++i)
            if (p[i] >= (1ull << 32)) is64 = 0;
        *flag = is64;
    }
}

__device__ __forceinline__ int load_idx(const void* p, int i, bool is64) {
    return is64 ? (int)((const long long*)p)[i] : ((const int*)p)[i];
}

// ---------------------------------------------------------------- x -> bf16 (both sides)
__global__ __launch_bounds__(256) void convert_x(const float* __restrict__ x1,
                                                 const float* __restrict__ x2,
                                                 ushort* __restrict__ o1,
                                                 ushort* __restrict__ o2) {
    const int per = NN * 16;
    const int i = blockIdx.x * 256 + threadIdx.x;
    const int side = i >= per;
    const int j = i - side * per;
    const float4 v = ((const float4*)(side ? x2 : x1))[j];
    ushort4 o;
    o.x = (ushort)f2b(v.x); o.y = (ushort)f2b(v.y);
    o.z = (ushort)f2b(v.z); o.w = (ushort)f2b(v.w);
    ((ushort4*)(side ? o2 : o1))[j] = o;
}

// ---------------------------------------------------------------- weights -> bf16 transposed WT[c][k]
__global__ __launch_bounds__(256) void prep_weights(const float* __restrict__ W1,
                                                    const float* __restrict__ W2,
                                                    const float* __restrict__ W3,
                                                    ushort* __restrict__ T1,
                                                    ushort* __restrict__ T2,
                                                    ushort* __restrict__ T3) {
    const int i = blockIdx.x * 256 + threadIdx.x;   // 40960 total
    if (i < 8192) {                 // W1: [64][128]
        const int k = i >> 7, c = i & 127;
        T1[c * 64 + k] = (ushort)f2b(W1[i]);
    } else if (i < 24576) {         // W2: [128][128]
        const int j = i - 8192, k = j >> 7, c = j & 127;
        T2[c * 128 + k] = (ushort)f2b(W2[j]);
    } else if (i < 40960) {         // W3
        const int j = i - 24576, k = j >> 7, c = j & 127;
        T3[c * 128 + k] = (ushort)f2b(W3[j]);
    }
}

// ---------------------------------------------------------------- CSR build
__global__ __launch_bounds__(256) void csr_hist2(const void* __restrict__ e1,
                                                 const void* __restrict__ e2,
                                                 int* __restrict__ degA,
                                                 int* __restrict__ degB,
                                                 const int* __restrict__ flag) {
    const bool is64 = (*flag != 0);
    const int i = blockIdx.x * 256 + threadIdx.x;
    if (i < 2 * NE) {
        const int side = i >= NE;
        const int j = i - side * NE;
        atomicAdd(&(side ? degB : degA)[load_idx(side ? e2 : e1, NE + j, is64)], 1);
    }
}

__global__ __launch_bounds__(256) void scan_block_sums2(const int* __restrict__ degA,
                                                        const int* __restrict__ degB,
                                                        int* __restrict__ bsum) {
    const int side = blockIdx.x >= SNB;
    const int bx = blockIdx.x - side * SNB;
    const int* deg = side ? degB : degA;
    const int t = threadIdx.x;
    const int base = bx * SB + t * 4;
    int s = 0;
    #pragma unroll
    for (int k = 0; k < 4; ++k) {
        const int i = base + k;
        if (i < NN) s += deg[i];
    }
    __shared__ int red[256];
    red[t] = s;
    __syncthreads();
    for (int off = 128; off > 0; off >>= 1) {
        if (t < off) red[t] += red[t + off];
        __syncthreads();
    }
    if (t == 0) bsum[side * 128 + bx] = red[0];
}

__global__ __launch_bounds__(128) void scan_bsums2(const int* __restrict__ bsum,
                                                   int* __restrict__ boff,
                                                   int* __restrict__ rpA,
                                                   int* __restrict__ rpB) {
    const int side = blockIdx.x;
    __shared__ int s[128];
    const int t = threadIdx.x;
    s[t] = (t < SNB) ? bsum[side * 128 + t] : 0;
    __syncthreads();
    for (int off = 1; off < 128; off <<= 1) {
        const int v = (t >= off) ? s[t - off] : 0;
        __syncthreads();
        s[t] += v;
        __syncthreads();
    }
    boff[side * 128 + t] = (t == 0) ? 0 : s[t - 1];
    if (t == 0) (side ? rpB : rpA)[NN] = s[SNB - 1];
}

__global__ __launch_bounds__(256) void scan_fill2(const int* __restrict__ degA,
                                                  const int* __restrict__ degB,
                                                  const int* __restrict__ boff,
                                                  int* __restrict__ rpA,
                                                  int* __restrict__ rpB,
                                                  int* __restrict__ curA,
                                                  int* __restrict__ curB) {
    const int side = blockIdx.x >= SNB;
    const int bx = blockIdx.x - side * SNB;
    const int* deg = side ? degB : degA;
    int* rowptr = side ? rpB : rpA;
    int* cursor = side ? curB : curA;
    const int t = threadIdx.x;
    const int base = bx * SB + t * 4;
    int v[4], s = 0;
    #pragma unroll
    for (int k = 0; k < 4; ++k) {
        const int i = base + k;
        v[k] = (i < NN) ? deg[i] : 0;
        s += v[k];
    }
    __shared__ int red[256];
    red[t] = s;
    __syncthreads();
    for (int off = 1; off < 256; off <<= 1) {
        const int x = (t >= off) ? red[t - off] : 0;
        __syncthreads();
        red[t] += x;
        __syncthreads();
    }
    int run = boff[side * 128 + bx] + ((t == 0) ? 0 : red[t - 1]);
    #pragma unroll
    for (int k = 0; k < 4; ++k) {
        const int i = base + k;
        if (i < NN) {
            rowptr[i] = run;
            cursor[i] = run;
            run += v[k];
        }
    }
}

// fill, dst-partitioned so each col region is written by one XCD (bid%8 ~ XCD round-robin).
__global__ __launch_bounds__(256) void csr_fill_part(const void* __restrict__ e1,
                                                     const void* __restrict__ e2,
                                                     int* __restrict__ curA,
                                                     int* __restrict__ curB,
                                                     int* __restrict__ colA,
                                                     int* __restrict__ colB,
                                                     const int* __restrict__ flag) {
    const bool is64 = (*flag != 0);
    const int g = blockIdx.x & 7;
    const int q = blockIdx.x >> 3;          // 0 .. 2*NCH-1
    const int side = q >= NCH;
    const int chunk = q - side * NCH;
    const void* __restrict__ e = side ? e2 : e1;
    int* __restrict__ cur = side ? curB : curA;
    int* __restrict__ col = side ? colB : colA;
    const int lo = g * PART;
    const int hi = min(lo + PART, NN);
    const int base = chunk * FCH;
    for (int i = base + threadIdx.x; i < base + FCH; i += 256) {
        const int d = load_idx(e, NE + i, is64);
        if (d >= lo && d < hi) {
            const int pos = atomicAdd(&cur[d], 1);
            col[pos] = load_idx(e, i, is64);
        }
    }
}

// ---------------------------------------------------------------- layer-1 gather (F=64, pure sum)
// XCD side-split: xcd 0-3 -> side A, 4-7 -> side B (halves per-XCD L2 working set)
struct G64Args {
    const ushort *xA, *xB;
    const int *rpA, *rpB, *colA, *colB;
    ushort *oA, *oB;
};

__global__ __launch_bounds__(256) void gather64k(G64Args a) {
    const int xcd = blockIdx.x & 7;
    const int side = xcd >> 2;
    const int bx = (blockIdx.x >> 3) * 4 + (xcd & 3);   // 0..24999
    const ushort* __restrict__ x = side ? a.xB : a.xA;
    const int* __restrict__ rowptr = side ? a.rpB : a.rpA;
    const int* __restrict__ col = side ? a.colB : a.colA;
    ushort* __restrict__ out = side ? a.oB : a.oA;

    const int node = (bx * 256 + threadIdx.x) >> 6;
    const int lane = threadIdx.x & 63;
    if (node >= NN) return;
    const int beg = rowptr[node], end = rowptr[node + 1];
    float acc = bf2f(x[node * 64 + lane]);
    int e = beg;
    for (; e + 3 < end; e += 4) {
        const int s0 = col[e], s1 = col[e + 1], s2 = col[e + 2], s3 = col[e + 3];
        acc += bf2f(x[s0 * 64 + lane]) + bf2f(x[s1 * 64 + lane])
             + bf2f(x[s2 * 64 + lane]) + bf2f(x[s3 * 64 + lane]);
    }
    for (; e < end; ++e) acc += bf2f(x[col[e] * 64 + lane]);
    out[node * 64 + lane] = (ushort)f2b(acc);
}

// ---------------------------------------------------------------- post-GEMM gather (F=128, pure adds) + BN stats
// r[d] = y[d] + sum_{j->d} y[j]; stats (sum,sumsq of rounded r) accumulated in epilogue.
// 64 nodes/block (4 waves x 16 nodes); XCD side-split.
struct GPostArgs {
    const ushort *yA, *yB;
    const int *rpA, *rpB, *colA, *colB;
    ushort *rA, *rB;
    float *stA, *stB;
};

__global__ __launch_bounds__(256) void gather_post(GPostArgs a) {
    const int xcd = blockIdx.x & 7;
    const int side = xcd >> 2;
    const int bx = (blockIdx.x >> 3) * 4 + (xcd & 3);
    if (bx >= NBG) return;
    const ushort* __restrict__ y = side ? a.yB : a.yA;
    const int* __restrict__ rowptr = side ? a.rpB : a.rpA;
    const int* __restrict__ col = side ? a.colB : a.colA;
    ushort* __restrict__ r = side ? a.rB : a.rA;
    float* __restrict__ stats = side ? a.stB : a.stA;

    const int t = threadIdx.x;
    const int w = t >> 6, l = t & 63;
    const int c2 = l * 2;
    float s0 = 0.f, s1 = 0.f, q0 = 0.f, q1 = 0.f;

    for (int i = 0; i < 16; ++i) {
        const int node = bx * 64 + w * 16 + i;
        if (node >= NN) break;
        const int beg = rowptr[node], end = rowptr[node + 1];
        const unsigned int u0 = *(const unsigned int*)&y[(size_t)node * 128 + c2];
        float ax = bf2f(u0 & 0xffffu), ay = bf2f(u0 >> 16);
        int e = beg;
        for (; e + 3 < end; e += 4) {
            const int sa = col[e], sb = col[e + 1], sc = col[e + 2], sd = col[e + 3];
            const unsigned int ua = *(const unsigned int*)&y[(size_t)sa * 128 + c2];
            const unsigned int ub = *(const unsigned int*)&y[(size_t)sb * 128 + c2];
            const unsigned int uc = *(const unsigned int*)&y[(size_t)sc * 128 + c2];
            const unsigned int ud = *(const unsigned int*)&y[(size_t)sd * 128 + c2];
            ax += bf2f(ua & 0xffffu) + bf2f(ub & 0xffffu) + bf2f(uc & 0xffffu) + bf2f(ud & 0xffffu);
            ay += bf2f(ua >> 16) + bf2f(ub >> 16) + bf2f(uc >> 16) + bf2f(ud >> 16);
        }
        for (; e < end; ++e) {
            const unsigned int u = *(const unsigned int*)&y[(size_t)col[e] * 128 + c2];
            ax += bf2f(u & 0xffffu);
            ay += bf2f(u >> 16);
        }
        const unsigned int pk = f2b(ax) | (f2b(ay) << 16);
        *(unsigned int*)&r[(size_t)node * 128 + c2] = pk;
        const float e0 = bf2f(pk & 0xffffu), e1 = bf2f(pk >> 16);
        s0 += e0; s1 += e1;
        q0 = fmaf(e0, e0, q0); q1 = fmaf(e1, e1, q1);
    }

    __shared__ float red[512];
    red[w * 128 + c2] = s0; red[w * 128 + c2 + 1] = s1;
    __syncthreads();
    if (t < 128) {
        const float v = red[t] + red[128 + t] + red[256 + t] + red[384 + t];
        unsafeAtomicAdd(&stats[t], v);
    }
    __syncthreads();
    red[w * 128 + c2] = q0; red[w * 128 + c2 + 1] = q1;
    __syncthreads();
    if (t < 128) {
        const float v = red[t] + red[128 + t] + red[256 + t] + red[384 + t];
        unsafeAtomicAdd(&stats[128 + t], v);
    }
}

// ---------------------------------------------------------------- MFMA GEMM: C = f(M) @ W (bf16)
// f = APPLY_BN ? relu(bn(v)) (coefs from raw stats, applied during M staging) : identity.
// STATS: fused column stats of rounded C in epilogue (layer 1 only). No bias (zeros + BN-invariant).
struct GemmArgs {
    const ushort *mA, *mB;
    const ushort *WT;              // [128][FIN] bf16, transposed
    ushort *cA, *cB;
    float *stA, *stB;              // STATS: out; APPLY_BN: in (raw sums of M)
    const float *gamma, *beta;     // APPLY_BN only
};

template<int FIN, bool APPLY_BN, bool STATS>
__global__ __launch_bounds__(256) void gemm_mfma(GemmArgs g) {
    constexpr int FP = FIN + 8;          // padded LDS stride (bf16 units)
    constexpr int CPR = FIN / 8;         // 16B chunks per row
    const int side = blockIdx.x >= NBG;
    const int bx = blockIdx.x - side * NBG;
    const ushort* __restrict__ M = side ? g.mB : g.mA;
    ushort* __restrict__ C = side ? g.cB : g.cA;
    float* __restrict__ stats = side ? g.stB : g.stA;

    __shared__ ushort sh[64 * 136 + 128 * FP];
    ushort* Ml = sh;                     // M tile (stride FP); later C tile (stride 136)
    ushort* Wl = sh + 64 * 136;          // WT tile (stride FP); later stats red (fp32)

    const int t = threadIdx.x;
    const int w = t >> 6;                // wave 0..3
    const int l = t & 63;
    const int lr = l & 15;
    const int lg = l >> 4;
    const int r0 = bx * 64;

    // per-thread BN coefs for its 8 staging columns (k-dim = prev layer's feature dim)
    float ca[8], cb[8];
    if (APPLY_BN) {
        const float* __restrict__ st = stats;
        const int cc = (t % CPR) * 8;
        const float inv_n = 1.f / (float)NN;
        #pragma unroll
        for (int j = 0; j < 8; ++j) {
            const int c = cc + j;
            const float mu = st[c] * inv_n;
            const float var = st[128 + c] * inv_n - mu * mu;
            ca[j] = g.gamma[c] * rsqrtf(var + BN_EPS);
            cb[j] = fmaf(-mu, ca[j], g.beta[c]);
        }
    }

    // ---- stage f(M) (64 x FIN)
    #pragma unroll
    for (int it = 0; it < (64 * CPR) / 256; ++it) {
        const int cid = it * 256 + t;
        const int row = cid / CPR, cc = (cid % CPR) * 8;
        const int r = r0 + row;
        uint4 v = make_uint4(0u, 0u, 0u, 0u);
        if (r < NN) v = *(const uint4*)&M[(size_t)r * FIN + cc];
        if (APPLY_BN) {
            unsigned int vv[4] = {v.x, v.y, v.z, v.w};
            #pragma unroll
            for (int q2 = 0; q2 < 4; ++q2) {
                float e0 = bf2f(vv[q2] & 0xffffu), e1 = bf2f(vv[q2] >> 16);
                e0 = fmaxf(fmaf(e0, ca[2 * q2], cb[2 * q2]), 0.f);
                e1 = fmaxf(fmaf(e1, ca[2 * q2 + 1], cb[2 * q2 + 1]), 0.f);
                vv[q2] = f2b(e0) | (f2b(e1) << 16);
            }
            v = make_uint4(vv[0], vv[1], vv[2], vv[3]);
        }
        *(uint4*)&Ml[row * FP + cc] = v;
    }
    // ---- stage WT (128 x FIN)
    #pragma unroll
    for (int it = 0; it < (128 * CPR) / 256; ++it) {
        const int cid = it * 256 + t;
        const int c = cid / CPR, kk = (cid % CPR) * 8;
        *(uint4*)&Wl[c * FP + kk] = *(const uint4*)&g.WT[c * FIN + kk];
    }
    __syncthreads();

    f32x4 acc[4][2];
    #pragma unroll
    for (int fi = 0; fi < 4; ++fi)
        #pragma unroll
        for (int fj = 0; fj < 2; ++fj)
            acc[fi][fj] = (f32x4){0.f, 0.f, 0.f, 0.f};

    #pragma unroll
    for (int kc = 0; kc < FIN / 32; ++kc) {
        const int kb = kc * 32 + lg * 8;
        bf16x8 a[4], b[2];
        #pragma unroll
        for (int fi = 0; fi < 4; ++fi)
            a[fi] = *(const bf16x8*)&Ml[(fi * 16 + lr) * FP + kb];
        #pragma unroll
        for (int fj = 0; fj < 2; ++fj)
            b[fj] = *(const bf16x8*)&Wl[(w * 32 + fj * 16 + lr) * FP + kb];
        #pragma unroll
        for (int fi = 0; fi < 4; ++fi)
            #pragma unroll
            for (int fj = 0; fj < 2; ++fj)
                acc[fi][fj] = __builtin_amdgcn_mfma_f32_16x16x32_bf16(a[fi], b[fj], acc[fi][fj], 0, 0, 0);
    }
    __syncthreads();   // all LDS reads done; Ml/Wl reusable

    // ---- stage C tile (bf16) into Ml (stride 136); C/D layout: col=lane&15, row=(lane>>4)*4+j
    #pragma unroll
    for (int fi = 0; fi < 4; ++fi)
        #pragma unroll
        for (int fj = 0; fj < 2; ++fj)
            #pragma unroll
            for (int j = 0; j < 4; ++j) {
                const int row = fi * 16 + lg * 4 + j;
                const int c = w * 32 + fj * 16 + lr;
                Ml[row * 136 + c] = (ushort)f2b(acc[fi][fj][j]);
            }
    __syncthreads();

    // ---- epilogue: coalesced global store (+ BN partial stats for layer 1)
    const int ry = t >> 4, c0 = (t & 15) * 8;
    float sc[8], qc[8];
    if (STATS) {
        #pragma unroll
        for (int j = 0; j < 8; ++j) { sc[j] = 0.f; qc[j] = 0.f; }
    }
    #pragma unroll
    for (int i = 0; i < 4; ++i) {
        const int rr = ry * 4 + i;
        const int r = r0 + rr;
        if (r < NN) {
            const uint4 pk = *(const uint4*)&Ml[rr * 136 + c0];
            if (STATS) {
                const unsigned int uu[4] = {pk.x, pk.y, pk.z, pk.w};
                #pragma unroll
                for (int q2 = 0; q2 < 4; ++q2) {
                    const float e0 = bf2f(uu[q2] & 0xffffu);
                    const float e1 = bf2f(uu[q2] >> 16);
                    sc[2 * q2] += e0;       sc[2 * q2 + 1] += e1;
                    qc[2 * q2] = fmaf(e0, e0, qc[2 * q2]);
                    qc[2 * q2 + 1] = fmaf(e1, e1, qc[2 * q2 + 1]);
                }
            }
            *(uint4*)&C[(size_t)r * HID + c0] = pk;
        }
    }
    if (STATS) {
        float* red = (float*)Wl;             // 2048 floats
        #pragma unroll
        for (int j = 0; j < 8; ++j) red[ry * 128 + c0 + j] = sc[j];
        __syncthreads();
        if (t < 128) {
            float a = 0.f;
            #pragma unroll
            for (int k = 0; k < 16; ++k) a += red[k * 128 + t];
            unsafeAtomicAdd(&stats[t], a);
        }
        __syncthreads();
        #pragma unroll
        for (int j = 0; j < 8; ++j) red[ry * 128 + c0 + j] = qc[j];
        __syncthreads();
        if (t < 128) {
            float a = 0.f;
            #pragma unroll
            for (int k = 0; k < 16; ++k) a += red[k * 128 + t];
            unsafeAtomicAdd(&stats[128 + t], a);
        }
    }
}

// ---------------------------------------------------------------- pool, both sides, BN3+ReLU fused
struct PoolArgs {
    const ushort *hA, *hB;
    const void *btA, *btB;
    const float *stA, *stB;
    const float *gamma, *beta;
    float *pooled, *cnt;
    const int* flag;
};

__global__ __launch_bounds__(128) void pool16(PoolArgs p) {
    const int side = blockIdx.x >= NBG;
    const int bx = blockIdx.x - side * NBG;
    const ushort* __restrict__ h = side ? p.hB : p.hA;
    const void* __restrict__ batch = side ? p.btB : p.btA;
    const float* __restrict__ st = side ? p.stB : p.stA;
    float* pooled = p.pooled + side * NG * HID;
    float* cnt = p.cnt + side * NG;
    const bool is64 = (*p.flag != 0);
    const int c = threadIdx.x;

    const float inv_n = 1.f / (float)NN;
    const float mu = st[c] * inv_n;
    const float var = st[128 + c] * inv_n - mu * mu;
    const float ca = p.gamma[c] * rsqrtf(var + BN_EPS);
    const float cb = fmaf(-mu, ca, p.beta[c]);

    const int rbeg = bx * 64;
    if (rbeg >= NN) return;
    const int rend = min(rbeg + 64, NN);
    const int g0 = load_idx(batch, rbeg, is64);
    const int g1 = load_idx(batch, rend - 1, is64);
    if (g0 == g1) {
        float acc = 0.f;
        #pragma unroll 8
        for (int r = rbeg; r < rend; ++r)
            acc += fmaxf(fmaf(bf2f(h[r * HID + c]), ca, cb), 0.f);
        unsafeAtomicAdd(&pooled[g0 * HID + c], acc);
        if (c == 0) unsafeAtomicAdd(&cnt[g0], (float)(rend - rbeg));
        return;
    }
    int gprev = g0;
    float acc = 0.f; int run = 0;
    for (int r = rbeg; r < rend; ++r) {
        const int g = load_idx(batch, r, is64);
        if (g != gprev) {
            unsafeAtomicAdd(&pooled[gprev * HID + c], acc);
            if (c == 0) unsafeAtomicAdd(&cnt[gprev], (float)run);
            acc = 0.f; run = 0; gprev = g;
        }
        acc += fmaxf(fmaf(bf2f(h[r * HID + c]), ca, cb), 0.f);
        ++run;
    }
    unsafeAtomicAdd(&pooled[gprev * HID + c], acc);
    if (c == 0) unsafeAtomicAdd(&cnt[gprev], (float)run);
}

__global__ __launch_bounds__(64) void pool_proj(const float* __restrict__ pooled,
                                                const float* __restrict__ cnt,
                                                const float* __restrict__ Wf,
                                                const float* __restrict__ bf,
                                                float* __restrict__ v) {
    const int side = blockIdx.x >= NG;
    const int g = blockIdx.x - side * NG;
    const int c = threadIdx.x;  // 64
    const float* pp = pooled + side * NG * HID + g * HID;
    const float inv = 1.f / fmaxf(cnt[side * NG + g], 1.f);
    float acc = 0.f;
    for (int k = 0; k < HID; ++k) acc = fmaf(pp[k], Wf[k * EMB + c], acc);
    v[side * NG * EMB + g * EMB + c] = fmaf(acc, inv, bf[c]);
}

// ---------------------------------------------------------------- classifier head
__global__ __launch_bounds__(256) void classifier(const float* __restrict__ v1,
                                                  const float* __restrict__ v2,
                                                  const float* __restrict__ Wc1,
                                                  const float* __restrict__ bc1,
                                                  const float* __restrict__ Wc2,
                                                  const float* __restrict__ bc2,
                                                  float* __restrict__ out) {
    const int g = threadIdx.x;
    if (g >= NG) return;
    float d[EMB];
    #pragma unroll
    for (int c = 0; c < EMB; ++c) d[c] = fabsf(v1[g * EMB + c] - v2[g * EMB + c]);
    float o = bc2[0];
    for (int j = 0; j < 32; ++j) {
        float h = bc1[j];
        #pragma unroll
        for (int c = 0; c < EMB; ++c) h = fmaf(d[c], Wc1[c * 32 + j], h);
        h = fmaxf(h, 0.f);
        o = fmaf(h, Wc2[j], o);
    }
    out[g] = 1.f / (1.f + expf(-o));
}

// ---------------------------------------------------------------- launch
extern "C" void kernel_launch(void* const* d_in, const int* in_sizes, int n_in,
                              void* d_out, int out_size, void* d_ws, size_t ws_size,
                              hipStream_t stream) {
    const float* x1 = (const float*)d_in[0];
    const float* x2 = (const float*)d_in[1];
    const void* ei1 = d_in[2];
    const void* ei2 = d_in[3];
    const void* bt1 = d_in[4];
    const void* bt2 = d_in[5];
    const float* W[3]  = {(const float*)d_in[6],  (const float*)d_in[10], (const float*)d_in[14]};
    const float* gg[3] = {(const float*)d_in[8],  (const float*)d_in[12], (const float*)d_in[16]};
    const float* be[3] = {(const float*)d_in[9],  (const float*)d_in[13], (const float*)d_in[17]};
    const float* Wf  = (const float*)d_in[18];
    const float* bfv = (const float*)d_in[19];
    const float* Wc1 = (const float*)d_in[20];
    const float* bc1 = (const float*)d_in[21];
    const float* Wc2 = (const float*)d_in[22];
    const float* bc2 = (const float*)d_in[23];

    // ---- workspace carve-up (256B-aligned)
    char* cur = (char*)d_ws;
    auto alloc = [&](size_t bytes) -> void* {
        void* p = cur;
        cur += (bytes + 255) & ~(size_t)255;
        return p;
    };
    ushort* P0 = (ushort*)alloc((size_t)NN * HID * 2);   // side0: x16 / r1 / r2 / r3
    ushort* P1 = (ushort*)alloc((size_t)NN * HID * 2);
    ushort* Q0 = (ushort*)alloc((size_t)NN * HID * 2);   // side0: agg1 / y2 / y3
    ushort* Q1 = (ushort*)alloc((size_t)NN * HID * 2);
    int* deg2   = (int*)alloc((size_t)2 * NN * 4);
    int* rpA    = (int*)alloc((size_t)(NN + 1) * 4);
    int* rpB    = (int*)alloc((size_t)(NN + 1) * 4);
    int* curA   = (int*)alloc((size_t)NN * 4);
    int* curB   = (int*)alloc((size_t)NN * 4);
    int* bsum   = (int*)alloc(256 * 4);
    int* boff   = (int*)alloc(256 * 4);
    int* colA   = (int*)alloc((size_t)NE * 4);
    int* colB   = (int*)alloc((size_t)NE * 4);
    int* flag   = (int*)alloc(64);
    ushort* WT1 = (ushort*)alloc(128 * 64 * 2);
    ushort* WT2 = (ushort*)alloc(128 * 128 * 2);
    ushort* WT3 = (ushort*)alloc(128 * 128 * 2);
    float* zreg = (float*)alloc((size_t)(6 * 256 + 2 * NG * HID + 2 * NG) * 4);
    float* stats  = zreg;                         // 6 x 256 (sum[128], sumsq[128])
    float* pooled = stats + 6 * 256;              // 2 x G x 128
    float* cnt    = pooled + 2 * NG * HID;        // 2 x G
    float* vv     = (float*)alloc((size_t)2 * NG * EMB * 4);
    int* degA = deg2, *degB = deg2 + NN;

    hipMemsetAsync(deg2, 0, (size_t)2 * NN * 4, stream);
    hipMemsetAsync(zreg, 0, (size_t)(6 * 256 + 2 * NG * HID + 2 * NG) * 4, stream);
    detect_i64_kernel<<<1, 64, 0, stream>>>(ei1, flag);
    convert_x<<<(2 * NN * 16) / 256, 256, 0, stream>>>(x1, x2, P0, P1);
    prep_weights<<<160, 256, 0, stream>>>(W[0], W[1], W[2], WT1, WT2, WT3);

    // ---- CSR build (both sides fused; XCD-partitioned fill)
    const int EB2 = (2 * NE + 255) / 256;
    csr_hist2<<<EB2, 256, 0, stream>>>(ei1, ei2, degA, degB, flag);
    scan_block_sums2<<<2 * SNB, 256, 0, stream>>>(degA, degB, bsum);
    scan_bsums2<<<2, 128, 0, stream>>>(bsum, boff, rpA, rpB);
    scan_fill2<<<2 * SNB, 256, 0, stream>>>(degA, degB, boff, rpA, rpB, curA, curB);
    csr_fill_part<<<8 * 2 * NCH, 256, 0, stream>>>(ei1, ei2, curA, curB, colA, colB, flag);

    float* st1A = stats + 0 * 256, *st1B = stats + 1 * 256;   // stats of r1 (BN1)
    float* st2A = stats + 2 * 256, *st2B = stats + 3 * 256;   // stats of r2 (BN2)
    float* st3A = stats + 4 * 256, *st3B = stats + 5 * 256;   // stats of r3 (BN3)

    const int GP = 8 * ((NBG + 3) / 4);   // gather_post grid = 3128

    // ---- layer 1: agg1 = (1+A)x16  P->Q ;  r1 = agg1 @ W1 -> P (+stats1)
    {
        G64Args a = {P0, P1, rpA, rpB, colA, colB, Q0, Q1};
        gather64k<<<8 * (NB4 / 4), 256, 0, stream>>>(a);
        GemmArgs g = {Q0, Q1, WT1, P0, P1, st1A, st1B, nullptr, nullptr};
        gemm_mfma<64, false, true><<<2 * NBG, 256, 0, stream>>>(g);
    }
    // ---- layer 2 (linearity swap): y2 = f1(r1) @ W2  P->Q ;  r2 = (1+A)y2 -> P (+stats2)
    {
        GemmArgs g = {P0, P1, WT2, Q0, Q1, st1A, st1B, gg[0], be[0]};
        gemm_mfma<128, true, false><<<2 * NBG, 256, 0, stream>>>(g);
        GPostArgs a = {Q0, Q1, rpA, rpB, colA, colB, P0, P1, st2A, st2B};
        gather_post<<<GP, 256, 0, stream>>>(a);
    }
    // ---- layer 3: y3 = f2(r2) @ W3  P->Q ;  r3 = (1+A)y3 -> P (+stats3)
    {
        GemmArgs g = {P0, P1, WT3, Q0, Q1, st2A, st2B, gg[1], be[1]};
        gemm_mfma<128, true, false><<<2 * NBG, 256, 0, stream>>>(g);
        GPostArgs a = {Q0, Q1, rpA, rpB, colA, colB, P0, P1, st3A, st3B};
        gather_post<<<GP, 256, 0, stream>>>(a);
    }
    // ---- pool (BN3+ReLU fused), projection, classifier
    {
        PoolArgs p = {P0, P1, bt1, bt2, st3A, st3B, gg[2], be[2], pooled, cnt, flag};
        pool16<<<2 * NBG, 128, 0, stream>>>(p);
    }
    pool_proj<<<2 * NG, 64, 0, stream>>>(pooled, cnt, Wf, bfv, vv);
    classifier<<<1, 256, 0, stream>>>(vv, vv + NG * EMB, Wc1, bc1, Wc2, bc2, (float*)d_out);
}